// Round 4
// baseline (700.492 us; speedup 1.0000x reference)
//
#include <hip/hip_runtime.h>
#include <hip/hip_bf16.h>

typedef unsigned short u16;
typedef unsigned int u32;

__device__ __forceinline__ float bf2f(u16 h) {
    return __uint_as_float(((u32)h) << 16);
}
__device__ __forceinline__ u16 f2bf(float f) {
    __hip_bfloat16 h = __float2bfloat16(f);   // RNE
    return *reinterpret_cast<u16*>(&h);
}

#define MEGA_GRID 768          // 256 CU x 3 blocks/CU (LDS-limited, see launch_bounds)
#define SPMM_ROWS 32
#define SPMM_LDSE 2048
// smem layout: As[64*132]f @0 (33792B) | Bs[64*64]f @33792 (16384B) | sums[128]f @50176 (512B)
#define MEGA_LDS  50688

// ---------- write path: MALL-direct (agent-scope relaxed) ----------
// All cross-phase intermediate WRITES go through these. They bypass L1/L2 and
// land at the Infinity-Cache coherence point (proven correct fence-free in R3).
// => L2 never holds DIRTY intermediate lines => barriers need no writeback.
__device__ __forceinline__ void stw(u32* p, u32 v) {
    __hip_atomic_store(p, v, __ATOMIC_RELAXED, __HIP_MEMORY_SCOPE_AGENT);
}
__device__ __forceinline__ void sti(int* p, int v) {
    __hip_atomic_store(p, v, __ATOMIC_RELAXED, __HIP_MEMORY_SCOPE_AGENT);
}
__device__ __forceinline__ void stf(float* p, float v) {
    __hip_atomic_store(p, v, __ATOMIC_RELAXED, __HIP_MEMORY_SCOPE_AGENT);
}
// READS of intermediates use plain cached loads (L1/L2 speed); staleness is
// handled by the acquire fence (flash invalidate) in grid_bar below.
__device__ __forceinline__ float lo16f(u32 w) { return __uint_as_float(w << 16); }
__device__ __forceinline__ float hi16f(u32 w) { return __uint_as_float(w & 0xffff0000u); }
__device__ __forceinline__ u32 packbf(float a, float b) {
    return (u32)f2bf(a) | ((u32)f2bf(b) << 16);
}

// ---- device-wide barrier: relaxed arrive/spin + ONE acquire fence ----
// Writes are already at the MALL (stw) when __syncthreads drains vmcnt, so no
// release fence / wbl2 is needed. After the count is reached, a single acquire
// fence (s_waitcnt + flash buffer_inv, no dirty-walk) discards stale CLEAN
// lines so the next phase's cached reads refetch from the MALL.
__device__ __forceinline__ void grid_bar(int* bar, int epoch) {
    __syncthreads();    // drains this block's vmem (vmcnt 0) before arrival
    if (threadIdx.x == 0) {
        __hip_atomic_fetch_add(bar, 1, __ATOMIC_RELAXED, __HIP_MEMORY_SCOPE_AGENT);
        const int tgt = epoch * MEGA_GRID;
        while (__hip_atomic_load(bar, __ATOMIC_RELAXED, __HIP_MEMORY_SCOPE_AGENT) < tgt)
            __builtin_amdgcn_s_sleep(4);
        __builtin_amdgcn_fence(__ATOMIC_ACQUIRE, "agent");   // flash inv L1+L2
    }
    __syncthreads();
}

// ---- distributed scan, 3 sub-phases ----
// P2a: block b sums its chunk of cnt -> partial[b]
__device__ void scan_partial(char* smem, const int* cnt, int* partial, int n) {
    int* sc = (int*)smem;
    const int per = (n + MEGA_GRID - 1) / MEGA_GRID;   // <=256 guarded by host
    const int s = (int)blockIdx.x * per;
    const int t = threadIdx.x;
    int i = s + t;
    int v = (t < per && i < n) ? cnt[i] : 0;
    sc[t] = v;
    __syncthreads();
    #pragma unroll
    for (int off = 128; off > 0; off >>= 1) {
        if (t < off) sc[t] += sc[t + off];
        __syncthreads();
    }
    if (t == 0) sti(partial + blockIdx.x, sc[0]);
}

// P2b: block 0 exclusive-scans partial[0..MEGA_GRID)
__device__ void scan_bases(char* smem, int* partial) {
    if (blockIdx.x != 0) return;
    int* sc = (int*)smem;
    const int t = threadIdx.x;
    const int K = (MEGA_GRID + 255) / 256;   // 3
    int p[K];
    int lsum = 0;
    #pragma unroll
    for (int j = 0; j < K; ++j) {
        int idx = t * K + j;
        p[j] = (idx < MEGA_GRID) ? partial[idx] : 0;
        lsum += p[j];
    }
    sc[t] = lsum;
    __syncthreads();
    #pragma unroll
    for (int off = 1; off < 256; off <<= 1) {
        int u = (t >= off) ? sc[t - off] : 0;
        __syncthreads();
        sc[t] += u;
        __syncthreads();
    }
    int run = sc[t] - lsum;   // exclusive prefix of this thread's group
    #pragma unroll
    for (int j = 0; j < K; ++j) {
        int idx = t * K + j;
        if (idx < MEGA_GRID) sti(partial + idx, run);
        run += p[j];
    }
}

// P2c: block b scans its chunk -> rowptr/cursor/dis
__device__ void scan_final(char* smem, const int* cnt, const int* partial,
                           int* rowptr, int* cursor, float* dis, int n, int E) {
    int* sc = (int*)smem;
    const int per = (n + MEGA_GRID - 1) / MEGA_GRID;
    const int s = (int)blockIdx.x * per;
    const int t = threadIdx.x;
    int i = s + t;
    bool act = (t < per && i < n);
    int v = act ? cnt[i] : 0;
    sc[t] = v;
    __syncthreads();
    #pragma unroll
    for (int off = 1; off < 256; off <<= 1) {
        int u = (t >= off) ? sc[t - off] : 0;
        __syncthreads();
        sc[t] += u;
        __syncthreads();
    }
    int excl = sc[t] - v;
    if (act) {
        int rp = partial[blockIdx.x] + excl;
        sti(rowptr + i, rp);
        sti(cursor + i, rp);
        stf(dis + i, (v > 0) ? rsqrtf((float)v) : 0.0f);
    }
    if (blockIdx.x == 0 && t == 0) sti(rowptr + n, E);
}

// ---- phase: CSR SpMM (tilde form), grid-strided over 32-row groups ----
__device__ void spmm_phase(char* smem,
    const u16* __restrict__ in, const u16* __restrict__ addsrc,
    u16* __restrict__ out1, u16* __restrict__ out2,
    const int* __restrict__ rowptr, const u32* __restrict__ ecol,
    const float* __restrict__ dis, const float* __restrict__ b,
    int relu, int sq1, int n)
{
    u32* eld = (u32*)smem;
    const u32* inw = (const u32*)in;
    const int ngroups = (n + SPMM_ROWS - 1) / SPMM_ROWS;
    const int lr = threadIdx.x >> 3;
    const int q  = threadIdx.x & 7;
    for (int g = blockIdx.x; g < ngroups; g += MEGA_GRID) {
        const int r0 = g * SPMM_ROWS;
        const int rend = min(n, r0 + SPMM_ROWS);
        const int estart = rowptr[r0];
        const int eendb  = rowptr[rend];
        const int ne = eendb - estart;
        const bool lds_ok = (ne <= SPMM_LDSE);
        if (lds_ok) {
            for (int j = threadIdx.x; j < ne; j += 256)
                eld[j] = ecol[estart + j];
        }
        __syncthreads();
        const int r = r0 + lr;
        if (r < n) {
            int e0 = rowptr[r], e1 = rowptr[r + 1];
            float ax0=0,ay0=0, ax1=0,ay1=0, ax2=0,ay2=0, ax3=0,ay3=0;
            if (lds_ok) {
                int le = e0 - estart, le1 = e1 - estart;
                for (; le + 4 <= le1; le += 4) {
                    u32 s0 = eld[le], s1 = eld[le+1], s2 = eld[le+2], s3 = eld[le+3];
                    u32 w0 = inw[(size_t)s0 * 8 + q];
                    u32 w1 = inw[(size_t)s1 * 8 + q];
                    u32 w2 = inw[(size_t)s2 * 8 + q];
                    u32 w3 = inw[(size_t)s3 * 8 + q];
                    ax0 += lo16f(w0); ay0 += hi16f(w0);
                    ax1 += lo16f(w1); ay1 += hi16f(w1);
                    ax2 += lo16f(w2); ay2 += hi16f(w2);
                    ax3 += lo16f(w3); ay3 += hi16f(w3);
                }
                for (; le < le1; ++le) {
                    u32 w0 = inw[(size_t)eld[le] * 8 + q];
                    ax0 += lo16f(w0); ay0 += hi16f(w0);
                }
            } else {
                int e = e0;
                for (; e + 4 <= e1; e += 4) {
                    u32 s0 = ecol[e], s1 = ecol[e+1], s2 = ecol[e+2], s3 = ecol[e+3];
                    u32 w0 = inw[(size_t)s0 * 8 + q];
                    u32 w1 = inw[(size_t)s1 * 8 + q];
                    u32 w2 = inw[(size_t)s2 * 8 + q];
                    u32 w3 = inw[(size_t)s3 * 8 + q];
                    ax0 += lo16f(w0); ay0 += hi16f(w0);
                    ax1 += lo16f(w1); ay1 += hi16f(w1);
                    ax2 += lo16f(w2); ay2 += hi16f(w2);
                    ax3 += lo16f(w3); ay3 += hi16f(w3);
                }
                for (; e < e1; ++e) {
                    u32 w0 = inw[(size_t)ecol[e] * 8 + q];
                    ax0 += lo16f(w0); ay0 += hi16f(w0);
                }
            }
            float Sx = (ax0 + ax1) + (ax2 + ax3);
            float Sy = (ay0 + ay1) + (ay2 + ay3);
            float d1 = dis[r];
            float sc1 = sq1 ? d1 * d1 : d1;
            float Ax = Sx * sc1, Ay = Sy * sc1;
            if (addsrc) {
                u32 s = ((const u32*)addsrc)[(size_t)r * 8 + q];
                Ax += lo16f(s); Ay += hi16f(s);
            }
            if (b) {
                Ax += b[2 * q];
                Ay += b[2 * q + 1];
            }
            if (relu) {
                Ax = fmaxf(Ax, 0.f);
                Ay = fmaxf(Ay, 0.f);
            }
            stw((u32*)out1 + (size_t)r * 8 + q, packbf(Ax, Ay));
            if (out2)
                stw((u32*)out2 + (size_t)r * 8 + q, packbf(Ax * d1, Ay * d1));
        }
        __syncthreads();   // WAR: protect eld before next group restage
    }
}

// ---- phase: GEMM1 (x @ W1 planes, row-normalize, tilde-scale planes 1..3) ----
__device__ void gemm1_phase(char* smem, const float* __restrict__ x,
                            const float* __restrict__ W1,
                            const float* __restrict__ dis,
                            u16* __restrict__ zb, int n, int nstride)
{
    float* As   = (float*)smem;
    float* Bs   = (float*)(smem + 33792);
    float* sums = (float*)(smem + 50176);
    const int t  = threadIdx.x;
    const int tx = t & 15;
    const int ty = t >> 4;
    const int c  = t & 15;
    const int g  = t >> 4;
    const int ntiles = (n + 127) >> 7;
    for (int tile = blockIdx.x; tile < ntiles; tile += MEGA_GRID) {
        const int block_row = tile << 7;
        float acc[8][4];
        #pragma unroll
        for (int i = 0; i < 8; ++i)
            #pragma unroll
            for (int j = 0; j < 4; ++j) acc[i][j] = 0.f;

        for (int kp = 0; kp < 2; ++kp) {
            #pragma unroll
            for (int i = 0; i < 8; ++i) {
                int row  = g + 16 * i;
                int grow = block_row + row;
                float v0 = 0.f, v1 = 0.f, v2 = 0.f, v3 = 0.f;
                if (grow < n) {
                    const float* xp = x + (long)grow * 128 + kp * 64 + c;
                    v0 = xp[0]; v1 = xp[16]; v2 = xp[32]; v3 = xp[48];
                }
                As[(c +  0) * 132 + row] = v0;
                As[(c + 16) * 132 + row] = v1;
                As[(c + 32) * 132 + row] = v2;
                As[(c + 48) * 132 + row] = v3;
                float red = (v0 + v1) + (v2 + v3);
                #pragma unroll
                for (int off = 8; off > 0; off >>= 1) red += __shfl_down(red, off, 16);
                if (c == 0) { if (kp == 0) sums[row] = red; else sums[row] += red; }
            }
            #pragma unroll
            for (int i2 = 0; i2 < 4; ++i2) {
                int kk = g + 16 * i2;
                int kglob = kp * 64 + kk;
                float4 wv = *(const float4*)(W1 + (c >> 2) * 2048 + kglob * 16 + 4 * (c & 3));
                *(float4*)(Bs + kk * 64 + 4 * c) = wv;
            }
            __syncthreads();
            #pragma unroll 4
            for (int kk = 0; kk < 64; ++kk) {
                float4 a0 = *(const float4*)(As + kk * 132 + 8 * ty);
                float4 a1 = *(const float4*)(As + kk * 132 + 8 * ty + 4);
                float4 bv = *(const float4*)(Bs + kk * 64 + 4 * tx);
                float ar[8] = {a0.x, a0.y, a0.z, a0.w, a1.x, a1.y, a1.z, a1.w};
                float br[4] = {bv.x, bv.y, bv.z, bv.w};
                #pragma unroll
                for (int i = 0; i < 8; ++i)
                    #pragma unroll
                    for (int j = 0; j < 4; ++j)
                        acc[i][j] += ar[i] * br[j];
            }
            __syncthreads();
        }
        int plane = tx >> 2;
        int oo4   = 4 * (tx & 3);
        #pragma unroll
        for (int i = 0; i < 8; ++i) {
            int row  = 8 * ty + i;
            int grow = block_row + row;
            if (grow < n) {
                float s = 1.0f / fmaxf(sums[row], 1e-8f);
                if (plane != 0) s *= dis[grow];          // tilde space for SpMM inputs
                u32* zp = (u32*)zb + (size_t)plane * (nstride >> 1) + (size_t)grow * 8 + (oo4 >> 1);
                stw(zp,     packbf(acc[i][0] * s, acc[i][1] * s));
                stw(zp + 1, packbf(acc[i][2] * s, acc[i][3] * s));
            }
        }
        __syncthreads();
    }
}

// ---- phase: GEMM2 (cat(P0..P3) @ W2cat + b2 -> fp32 out) ----
__device__ void gemm2_phase(char* smem, const u16* __restrict__ zb,
                            const float* __restrict__ W2,
                            const float* __restrict__ b2,
                            float* __restrict__ out, int n, int nstride)
{
    float* As = (float*)smem;
    float* Bs = (float*)(smem + 33792);
    const u32* zw = (const u32*)zb;
    const int nsw = nstride >> 1;     // u32 stride per plane
    const int t  = threadIdx.x;
    const int tx = t & 15;
    const int ty = t >> 4;
    const int c  = t & 15;
    const int g  = t >> 4;
    const int ntiles = (n + 127) >> 7;
    for (int tile = blockIdx.x; tile < ntiles; tile += MEGA_GRID) {
        const int block_row = tile << 7;
        float acc[8][4];
        #pragma unroll
        for (int i = 0; i < 8; ++i)
            #pragma unroll
            for (int j = 0; j < 4; ++j) acc[i][j] = 0.f;

        // staging: threads c=0..7 load pair c of planes 0,1; c=8..15 pair c-8 of planes 2,3
        #pragma unroll
        for (int i = 0; i < 8; ++i) {
            int row  = g + 16 * i;
            int grow = block_row + row;
            int pr   = c & 7;                       // pair index 0..7
            int pl   = (c < 8) ? 0 : 2;             // first plane this thread stages
            float l0 = 0.f, h0 = 0.f, l1 = 0.f, h1 = 0.f;
            if (grow < n) {
                u32 w0 = zw[(size_t)pl * nsw       + (size_t)grow * 8 + pr];
                u32 w1 = zw[(size_t)(pl + 1) * nsw + (size_t)grow * 8 + pr];
                l0 = lo16f(w0); h0 = hi16f(w0);
                l1 = lo16f(w1); h1 = hi16f(w1);
            }
            int col = pl * 16 + 2 * pr;
            As[(col +  0) * 132 + row] = l0;
            As[(col +  1) * 132 + row] = h0;
            As[(col + 16) * 132 + row] = l1;
            As[(col + 17) * 132 + row] = h1;
        }
        #pragma unroll
        for (int i2 = 0; i2 < 4; ++i2) {
            int j = g + 16 * i2;
            float4 wv = *(const float4*)(W2 + j * 64 + 4 * c);
            *(float4*)(Bs + j * 64 + 4 * c) = wv;
        }
        __syncthreads();
        #pragma unroll 4
        for (int kk = 0; kk < 64; ++kk) {
            float4 a0 = *(const float4*)(As + kk * 132 + 8 * ty);
            float4 a1 = *(const float4*)(As + kk * 132 + 8 * ty + 4);
            float4 bv = *(const float4*)(Bs + kk * 64 + 4 * tx);
            float ar[8] = {a0.x, a0.y, a0.z, a0.w, a1.x, a1.y, a1.z, a1.w};
            float br[4] = {bv.x, bv.y, bv.z, bv.w};
            #pragma unroll
            for (int i = 0; i < 8; ++i)
                #pragma unroll
                for (int j = 0; j < 4; ++j)
                    acc[i][j] += ar[i] * br[j];
        }
        float4 bias = *(const float4*)(b2 + 4 * tx);
        #pragma unroll
        for (int i = 0; i < 8; ++i) {
            int grow = block_row + 8 * ty + i;
            if (grow < n) {
                float4 o = make_float4(acc[i][0] + bias.x, acc[i][1] + bias.y,
                                       acc[i][2] + bias.z, acc[i][3] + bias.w);
                *(float4*)(out + (long)grow * 64 + 4 * tx) = o;   // flushed at kernel end
            }
        }
        __syncthreads();
    }
}

// ==================== the persistent mega-kernel ====================
__global__ __launch_bounds__(256, 3) void mega_kernel(
    const float* __restrict__ x, const int* __restrict__ srcp,
    const int* __restrict__ dstp,
    const float* __restrict__ W1, const float* __restrict__ b1,
    const float* __restrict__ W2, const float* __restrict__ b2,
    float* __restrict__ out,
    int* bar, int* cnt, int* rowptr, int* cursor, float* dis, int* partial,
    u16* zb, u32* ecol, int n, int E, int nstride)
{
    __shared__ __align__(16) char smem[MEGA_LDS];
    const int gstride = MEGA_GRID * 256;

    // P1: in-degree count (cnt zeroed by preceding memset; agent-scope RMW)
    for (int e = blockIdx.x * 256 + threadIdx.x; e < E; e += gstride)
        __hip_atomic_fetch_add(cnt + dstp[e], 1, __ATOMIC_RELAXED, __HIP_MEMORY_SCOPE_AGENT);
    grid_bar(bar, 1);

    // P2: distributed scan
    scan_partial(smem, cnt, partial, n);
    grid_bar(bar, 2);
    scan_bases(smem, partial);
    grid_bar(bar, 3);
    scan_final(smem, cnt, partial, rowptr, cursor, dis, n, E);
    grid_bar(bar, 4);

    // P3: scatter edges into CSR (atomic cursors) THEN gemm1 — independent
    for (int e = blockIdx.x * 256 + threadIdx.x; e < E; e += gstride) {
        int d = dstp[e];
        int p = __hip_atomic_fetch_add(cursor + d, 1, __ATOMIC_RELAXED, __HIP_MEMORY_SCOPE_AGENT);
        stw(ecol + p, (u32)srcp[e]);
    }
    gemm1_phase(smem, x, W1, dis, zb, n, nstride);
    grid_bar(bar, 5);

    u16 *P0 = zb, *P1 = zb + nstride, *P2 = zb + 2 * nstride, *P3 = zb + 3 * nstride;
    u16 *T0 = zb + 4 * nstride, *T1 = zb + 5 * nstride;

    // L1 Horner (tilde space: scale1 = dis^2)
    spmm_phase(smem, P3, P2, P2, nullptr, rowptr, ecol, dis, nullptr, 0, 1, n);
    grid_bar(bar, 6);
    spmm_phase(smem, P2, P1, P1, nullptr, rowptr, ecol, dis, nullptr, 0, 1, n);
    grid_bar(bar, 7);
    // h1 = relu(z0 + dis*S + b1); T0 = dis*h1
    spmm_phase(smem, P1, P0, P0, T0, rowptr, ecol, dis, b1, 1, 0, n);
    grid_bar(bar, 8);
    // L2 hops: g_k = dis*S (gemm2 input), tilde copy = dis*g_k
    spmm_phase(smem, T0, nullptr, P1, T1, rowptr, ecol, dis, nullptr, 0, 0, n);
    grid_bar(bar, 9);
    spmm_phase(smem, T1, nullptr, P2, T0, rowptr, ecol, dis, nullptr, 0, 0, n);
    grid_bar(bar, 10);
    spmm_phase(smem, T0, nullptr, P3, nullptr, rowptr, ecol, dis, nullptr, 0, 0, n);
    grid_bar(bar, 11);

    // P11: GEMM2 -> out
    gemm2_phase(smem, zb, W2, b2, out, n, nstride);
}

// ================= fp32 fallback path (small workspace) =================
__global__ void deg_kernel(const int* __restrict__ dst, float* __restrict__ deg, int E) {
    int e = blockIdx.x * blockDim.x + threadIdx.x;
    if (e < E) atomicAdd(&deg[dst[e]], 1.0f);
}
__global__ void disf_kernel(float* __restrict__ deg, int n) {
    int i = blockIdx.x * blockDim.x + threadIdx.x;
    if (i < n) {
        float d = deg[i];
        deg[i] = (d > 0.0f) ? rsqrtf(d) : 0.0f;
    }
}
__global__ __launch_bounds__(256) void gemm1_f32_kernel(
    const float* __restrict__ x, const float* __restrict__ W1,
    float* __restrict__ z, int n, int nstride)
{
    __shared__ float As[64 * 132];
    __shared__ float Bs[64 * 64];
    __shared__ float sums[128];
    const int t  = threadIdx.x;
    const int tx = t & 15;
    const int ty = t >> 4;
    const int c  = t & 15;
    const int g  = t >> 4;
    const int block_row = blockIdx.x * 128;
    float acc[8][4];
    #pragma unroll
    for (int i = 0; i < 8; ++i)
        #pragma unroll
        for (int j = 0; j < 4; ++j) acc[i][j] = 0.f;
    for (int kp = 0; kp < 2; ++kp) {
        #pragma unroll
        for (int i = 0; i < 8; ++i) {
            int row  = g + 16 * i;
            int grow = block_row + row;
            float v0 = 0.f, v1 = 0.f, v2 = 0.f, v3 = 0.f;
            if (grow < n) {
                const float* xp = x + (long)grow * 128 + kp * 64 + c;
                v0 = xp[0]; v1 = xp[16]; v2 = xp[32]; v3 = xp[48];
            }
            As[(c +  0) * 132 + row] = v0;
            As[(c + 16) * 132 + row] = v1;
            As[(c + 32) * 132 + row] = v2;
            As[(c + 48) * 132 + row] = v3;
            float red = (v0 + v1) + (v2 + v3);
            #pragma unroll
            for (int off = 8; off > 0; off >>= 1) red += __shfl_down(red, off, 16);
            if (c == 0) { if (kp == 0) sums[row] = red; else sums[row] += red; }
        }
        #pragma unroll
        for (int i2 = 0; i2 < 4; ++i2) {
            int kk = g + 16 * i2;
            int kglob = kp * 64 + kk;
            float4 wv = *(const float4*)(W1 + (c >> 2) * 2048 + kglob * 16 + 4 * (c & 3));
            *(float4*)(Bs + kk * 64 + 4 * c) = wv;
        }
        __syncthreads();
        #pragma unroll 4
        for (int kk = 0; kk < 64; ++kk) {
            float4 a0 = *(const float4*)(As + kk * 132 + 8 * ty);
            float4 a1 = *(const float4*)(As + kk * 132 + 8 * ty + 4);
            float4 bv = *(const float4*)(Bs + kk * 64 + 4 * tx);
            float ar[8] = {a0.x, a0.y, a0.z, a0.w, a1.x, a1.y, a1.z, a1.w};
            float br[4] = {bv.x, bv.y, bv.z, bv.w};
            #pragma unroll
            for (int i = 0; i < 8; ++i)
                #pragma unroll
                for (int j = 0; j < 4; ++j)
                    acc[i][j] += ar[i] * br[j];
        }
        __syncthreads();
    }
    int plane = tx >> 2;
    int oo4   = 4 * (tx & 3);
    #pragma unroll
    for (int i = 0; i < 8; ++i) {
        int row  = 8 * ty + i;
        int grow = block_row + row;
        if (grow < n) {
            float s = 1.0f / fmaxf(sums[row], 1e-8f);
            float4 o = make_float4(acc[i][0] * s, acc[i][1] * s, acc[i][2] * s, acc[i][3] * s);
            *(float4*)(z + (long)plane * nstride + (long)grow * 16 + oo4) = o;
        }
    }
}
__global__ __launch_bounds__(256) void spmm_atomic_kernel(
    const float* __restrict__ in, float* __restrict__ out,
    const int* __restrict__ src, const int* __restrict__ dst,
    const float* __restrict__ dis, int E)
{
    int t = blockIdx.x * blockDim.x + threadIdx.x;
    int e = t >> 4, f = t & 15;
    if (e < E) {
        int s = src[e], d = dst[e];
        atomicAdd(&out[d * 16 + f], dis[s] * dis[d] * in[s * 16 + f]);
    }
}
__global__ void bias_relu_kernel(float* __restrict__ z0, const float* __restrict__ b, int total) {
    int i = blockIdx.x * blockDim.x + threadIdx.x;
    if (i < total) {
        float v = z0[i] + b[i & 15];
        z0[i] = v > 0.0f ? v : 0.0f;
    }
}
__global__ __launch_bounds__(256) void gemm2_f32_kernel(
    const float* __restrict__ z, const float* __restrict__ W2,
    const float* __restrict__ b2, float* __restrict__ out, int n, int nstride)
{
    __shared__ float As[64 * 132];
    __shared__ float Bs[64 * 64];
    const int t  = threadIdx.x;
    const int tx = t & 15;
    const int ty = t >> 4;
    const int c  = t & 15;
    const int g  = t >> 4;
    const int block_row = blockIdx.x * 128;
    float acc[8][4];
    #pragma unroll
    for (int i = 0; i < 8; ++i)
        #pragma unroll
        for (int j = 0; j < 4; ++j) acc[i][j] = 0.f;
    #pragma unroll
    for (int i = 0; i < 8; ++i) {
        int row  = g + 16 * i;
        int grow = block_row + row;
        float v0 = 0.f, v1 = 0.f, v2 = 0.f, v3 = 0.f;
        if (grow < n) {
            const float* zp = z + (long)grow * 16 + c;
            v0 = zp[0];
            v1 = zp[(long)nstride];
            v2 = zp[2 * (long)nstride];
            v3 = zp[3 * (long)nstride];
        }
        As[(c +  0) * 132 + row] = v0;
        As[(c + 16) * 132 + row] = v1;
        As[(c + 32) * 132 + row] = v2;
        As[(c + 48) * 132 + row] = v3;
    }
    #pragma unroll
    for (int i2 = 0; i2 < 4; ++i2) {
        int j = g + 16 * i2;
        float4 wv = *(const float4*)(W2 + j * 64 + 4 * c);
        *(float4*)(Bs + j * 64 + 4 * c) = wv;
    }
    __syncthreads();
    #pragma unroll 4
    for (int kk = 0; kk < 64; ++kk) {
        float4 a0 = *(const float4*)(As + kk * 132 + 8 * ty);
        float4 a1 = *(const float4*)(As + kk * 132 + 8 * ty + 4);
        float4 bv = *(const float4*)(Bs + kk * 64 + 4 * tx);
        float ar[8] = {a0.x, a0.y, a0.z, a0.w, a1.x, a1.y, a1.z, a1.w};
        float br[4] = {bv.x, bv.y, bv.z, bv.w};
        #pragma unroll
        for (int i = 0; i < 8; ++i)
            #pragma unroll
            for (int j = 0; j < 4; ++j)
                acc[i][j] += ar[i] * br[j];
    }
    float4 bias = *(const float4*)(b2 + 4 * tx);
    #pragma unroll
    for (int i = 0; i < 8; ++i) {
        int grow = block_row + 8 * ty + i;
        if (grow < n) {
            float4 o = make_float4(acc[i][0] + bias.x, acc[i][1] + bias.y,
                                   acc[i][2] + bias.z, acc[i][3] + bias.w);
            *(float4*)(out + (long)grow * 64 + 4 * tx) = o;
        }
    }
}

static inline size_t align16(size_t v) { return (v + 15) & ~(size_t)15; }

extern "C" void kernel_launch(void* const* d_in, const int* in_sizes, int n_in,
                              void* d_out, int out_size, void* d_ws, size_t ws_size,
                              hipStream_t stream) {
    const float* x   = (const float*)d_in[0];
    const int*   ei  = (const int*)d_in[1];
    const float* W1  = (const float*)d_in[2];
    const float* b1  = (const float*)d_in[3];
    const float* W2  = (const float*)d_in[4];
    const float* bb2 = (const float*)d_in[5];
    float* out = (float*)d_out;

    const int n  = in_sizes[0] / 128;   // 50000
    const int E  = in_sizes[1] / 2;     // 800000
    const int NS = n * 16;

    const int* srcp = ei;
    const int* dstp = ei + E;

    char* wsb = (char*)d_ws;
    // layout: bar(16B) | cnt[n] | rowptr[n+1] | cursor[n] | dis[n] | partial[GRID] | zb[6*NS u16] | ecol[E u32]
    int*   bar    = (int*)wsb;
    int*   cnt    = (int*)(wsb + 16);
    int*   rowptr = (int*)(wsb + 16 + (size_t)4 * n);
    int*   cursor = (int*)(wsb + 16 + (size_t)4 * (2 * n + 1));
    float* dis    = (float*)(wsb + 16 + (size_t)4 * (3 * n + 1));
    int*   partial= (int*)(wsb + 16 + (size_t)4 * (4 * n + 1));
    size_t zoffb  = align16(16 + (size_t)4 * (4 * n + 1 + MEGA_GRID));
    u16*   zb     = (u16*)(wsb + zoffb);
    size_t ecooff = align16(zoffb + (size_t)2 * 6 * NS);
    u32*   ecol   = (u32*)(wsb + ecooff);
    size_t need   = ecooff + (size_t)4 * E;

    if (ws_size >= need && n <= MEGA_GRID * 256) {
        // zero bar counter + degree counts, then one persistent kernel for everything
        hipMemsetAsync(wsb, 0, 16 + (size_t)4 * n, stream);
        mega_kernel<<<MEGA_GRID, 256, 0, stream>>>(
            x, srcp, dstp, W1, b1, W2, bb2, out,
            bar, cnt, rowptr, cursor, dis, partial, zb, ecol, n, E, NS);
    } else {
        // ---------- fp32 atomic fallback ----------
        int gemm_blocks = (n + 127) / 128;
        float* ws = (float*)d_ws;
        float* dis2 = ws;
        size_t z2off = ((size_t)n + 3) & ~(size_t)3;
        float* z2 = ws + z2off;
        hipMemsetAsync(dis2, 0, n * sizeof(float), stream);
        deg_kernel<<<(E + 255) / 256, 256, 0, stream>>>(dstp, dis2, E);
        disf_kernel<<<(n + 255) / 256, 256, 0, stream>>>(dis2, n);
        gemm1_f32_kernel<<<gemm_blocks, 256, 0, stream>>>(x, W1, z2, n, NS);
        int sb = (16 * E + 255) / 256;
        spmm_atomic_kernel<<<sb, 256, 0, stream>>>(z2 + 3 * NS, z2 + 2 * NS, srcp, dstp, dis2, E);
        spmm_atomic_kernel<<<sb, 256, 0, stream>>>(z2 + 2 * NS, z2 + 1 * NS, srcp, dstp, dis2, E);
        spmm_atomic_kernel<<<sb, 256, 0, stream>>>(z2 + 1 * NS, z2,          srcp, dstp, dis2, E);
        bias_relu_kernel<<<(NS + 255) / 256, 256, 0, stream>>>(z2, b1, NS);
        hipMemsetAsync(z2 + NS, 0, (size_t)3 * NS * sizeof(float), stream);
        spmm_atomic_kernel<<<sb, 256, 0, stream>>>(z2,          z2 + NS,     srcp, dstp, dis2, E);
        spmm_atomic_kernel<<<sb, 256, 0, stream>>>(z2 + NS,     z2 + 2 * NS, srcp, dstp, dis2, E);
        spmm_atomic_kernel<<<sb, 256, 0, stream>>>(z2 + 2 * NS, z2 + 3 * NS, srcp, dstp, dis2, E);
        gemm2_f32_kernel<<<gemm_blocks, 256, 0, stream>>>(z2, W2, bb2, out, n, NS);
    }
}

// Round 5
// 350.960 us; speedup vs baseline: 1.9959x; 1.9959x over previous
//
#include <hip/hip_runtime.h>
#include <hip/hip_bf16.h>

typedef unsigned short u16;
typedef unsigned int u32;

__device__ __forceinline__ float bf2f(u16 h) {
    return __uint_as_float(((u32)h) << 16);
}
__device__ __forceinline__ u16 f2bf(float f) {
    __hip_bfloat16 h = __float2bfloat16(f);   // RNE
    return *reinterpret_cast<u16*>(&h);
}

#define MEGA_GRID 768          // 256 CU x 3 blocks/CU (LDS-limited, see launch_bounds)
#define SPMM_ROWS 32
#define SPMM_LDSE 2048
// smem layout: As[64*132]f @0 (33792B) | Bs[64*64]f @33792 (16384B) | sums[128]f @50176 (512B)
#define MEGA_LDS  50688
#define BAR_GROUPS 48
#define BAR_GSIZE  16          // 48*16 = 768

// ---------- MALL-direct accessors (agent-scope relaxed; bypass L1/L2) ----------
// ALL intermediate WRITES go through these (R3-proven fence-free-correct).
// Reads are plain cached EXCEPT where noted (gemm2 staging, barrier words):
// the dataflow is single-assignment w.r.t. cached reads, so no stale line
// can exist and NO cache maintenance op is ever needed.
__device__ __forceinline__ void stw(u32* p, u32 v) {
    __hip_atomic_store(p, v, __ATOMIC_RELAXED, __HIP_MEMORY_SCOPE_AGENT);
}
__device__ __forceinline__ void sti(int* p, int v) {
    __hip_atomic_store(p, v, __ATOMIC_RELAXED, __HIP_MEMORY_SCOPE_AGENT);
}
__device__ __forceinline__ void stf(float* p, float v) {
    __hip_atomic_store(p, v, __ATOMIC_RELAXED, __HIP_MEMORY_SCOPE_AGENT);
}
__device__ __forceinline__ u32 ldw(const u32* p) {
    return __hip_atomic_load((u32*)p, __ATOMIC_RELAXED, __HIP_MEMORY_SCOPE_AGENT);
}
__device__ __forceinline__ int ldi(const int* p) {
    return __hip_atomic_load((int*)p, __ATOMIC_RELAXED, __HIP_MEMORY_SCOPE_AGENT);
}
__device__ __forceinline__ int aadd(int* p) {
    return __hip_atomic_fetch_add(p, 1, __ATOMIC_RELAXED, __HIP_MEMORY_SCOPE_AGENT);
}
__device__ __forceinline__ float lo16f(u32 w) { return __uint_as_float(w << 16); }
__device__ __forceinline__ float hi16f(u32 w) { return __uint_as_float(w & 0xffff0000u); }
__device__ __forceinline__ u32 packbf(float a, float b) {
    return (u32)f2bf(a) | ((u32)f2bf(b) << 16);
}

// ---- device-wide barrier: hierarchical arrival + separate release word ----
// Previous rounds RMW'd and polled the SAME MALL line: 768 fetch_adds queued
// behind thousands of poll reads. Here: 48 group counters (64B-strided) take
// 16 RMWs each in parallel; group-finishers RMW a root counter (48 RMWs);
// the last one stores `release`=epoch on its own line; everyone polls ONLY
// the read-only release line. Zero cache maintenance (see dataflow note).
__device__ __forceinline__ void grid_bar(int* barr, int epoch) {
    __syncthreads();    // drains this block's vmem (all MALL stores acked)
    if (threadIdx.x == 0) {
        const int g = (int)blockIdx.x % BAR_GROUPS;
        int old = aadd(barr + g * 16);
        if (old == epoch * BAR_GSIZE - 1) {          // last of group this epoch
            int r = aadd(barr + 768);
            if (r == epoch * BAR_GROUPS - 1)         // last group
                sti(barr + 784, epoch);
        }
        while (ldi(barr + 784) < epoch)
            __builtin_amdgcn_s_sleep(16);
    }
    __syncthreads();
}

// ---- fused scan phase: each block redundantly base-sums cnt[0..s) (L2-hot),
// then scans its own chunk -> rowptr/cursor/dis. ONE phase, no partial array.
__device__ void scan_all(char* smem, const int* cnt, int* rowptr, int* cursor,
                         float* dis, int n, int E) {
    int* sc = (int*)smem;
    const int per = (n + MEGA_GRID - 1) / MEGA_GRID;    // <=256 (host guard)
    const int s = (int)blockIdx.x * per;
    const int t = threadIdx.x;
    // base = sum cnt[0..min(s,n))
    const int slim = min(s, n);
    int local = 0;
    for (int i = t; i < slim; i += 256) local += cnt[i];
    sc[t] = local;
    __syncthreads();
    #pragma unroll
    for (int off = 128; off > 0; off >>= 1) {
        if (t < off) sc[t] += sc[t + off];
        __syncthreads();
    }
    const int base = sc[0];
    __syncthreads();
    // exclusive scan of this block's chunk
    int i = s + t;
    bool act = (t < per && i < n);
    int v = act ? cnt[i] : 0;
    sc[t] = v;
    __syncthreads();
    #pragma unroll
    for (int off = 1; off < 256; off <<= 1) {
        int u = (t >= off) ? sc[t - off] : 0;
        __syncthreads();
        sc[t] += u;
        __syncthreads();
    }
    int excl = sc[t] - v;
    if (act) {
        int rp = base + excl;
        sti(rowptr + i, rp);
        sti(cursor + i, rp);
        stf(dis + i, (v > 0) ? rsqrtf((float)v) : 0.0f);
    }
    if (blockIdx.x == 0 && t == 0) sti(rowptr + n, E);
}

// ---- phase: CSR SpMM (tilde form), grid-strided over 32-row groups ----
// All reads cached (in/addsrc/rowptr/ecol/dis are single-assignment before
// first read); outputs MALL-direct.
__device__ void spmm_phase(char* smem,
    const u16* __restrict__ in, const u16* __restrict__ addsrc,
    u16* __restrict__ out1, u16* __restrict__ out2,
    const int* __restrict__ rowptr, const u32* __restrict__ ecol,
    const float* __restrict__ dis, const float* __restrict__ b,
    int relu, int sq1, int n)
{
    u32* eld = (u32*)smem;
    const u32* inw = (const u32*)in;
    const int ngroups = (n + SPMM_ROWS - 1) / SPMM_ROWS;
    const int lr = threadIdx.x >> 3;
    const int q  = threadIdx.x & 7;
    for (int g = blockIdx.x; g < ngroups; g += MEGA_GRID) {
        const int r0 = g * SPMM_ROWS;
        const int rend = min(n, r0 + SPMM_ROWS);
        const int estart = rowptr[r0];
        const int eendb  = rowptr[rend];
        const int ne = eendb - estart;
        const bool lds_ok = (ne <= SPMM_LDSE);
        if (lds_ok) {
            for (int j = threadIdx.x; j < ne; j += 256)
                eld[j] = ecol[estart + j];
        }
        __syncthreads();
        const int r = r0 + lr;
        if (r < n) {
            int e0 = rowptr[r], e1 = rowptr[r + 1];
            float ax0=0,ay0=0, ax1=0,ay1=0, ax2=0,ay2=0, ax3=0,ay3=0;
            if (lds_ok) {
                int le = e0 - estart, le1 = e1 - estart;
                for (; le + 4 <= le1; le += 4) {
                    u32 s0 = eld[le], s1 = eld[le+1], s2 = eld[le+2], s3 = eld[le+3];
                    u32 w0 = inw[(size_t)s0 * 8 + q];
                    u32 w1 = inw[(size_t)s1 * 8 + q];
                    u32 w2 = inw[(size_t)s2 * 8 + q];
                    u32 w3 = inw[(size_t)s3 * 8 + q];
                    ax0 += lo16f(w0); ay0 += hi16f(w0);
                    ax1 += lo16f(w1); ay1 += hi16f(w1);
                    ax2 += lo16f(w2); ay2 += hi16f(w2);
                    ax3 += lo16f(w3); ay3 += hi16f(w3);
                }
                for (; le < le1; ++le) {
                    u32 w0 = inw[(size_t)eld[le] * 8 + q];
                    ax0 += lo16f(w0); ay0 += hi16f(w0);
                }
            } else {
                int e = e0;
                for (; e + 4 <= e1; e += 4) {
                    u32 s0 = ecol[e], s1 = ecol[e+1], s2 = ecol[e+2], s3 = ecol[e+3];
                    u32 w0 = inw[(size_t)s0 * 8 + q];
                    u32 w1 = inw[(size_t)s1 * 8 + q];
                    u32 w2 = inw[(size_t)s2 * 8 + q];
                    u32 w3 = inw[(size_t)s3 * 8 + q];
                    ax0 += lo16f(w0); ay0 += hi16f(w0);
                    ax1 += lo16f(w1); ay1 += hi16f(w1);
                    ax2 += lo16f(w2); ay2 += hi16f(w2);
                    ax3 += lo16f(w3); ay3 += hi16f(w3);
                }
                for (; e < e1; ++e) {
                    u32 w0 = inw[(size_t)ecol[e] * 8 + q];
                    ax0 += lo16f(w0); ay0 += hi16f(w0);
                }
            }
            float Sx = (ax0 + ax1) + (ax2 + ax3);
            float Sy = (ay0 + ay1) + (ay2 + ay3);
            float d1 = dis[r];
            float sc1 = sq1 ? d1 * d1 : d1;
            float Ax = Sx * sc1, Ay = Sy * sc1;
            if (addsrc) {
                u32 s = ((const u32*)addsrc)[(size_t)r * 8 + q];
                Ax += lo16f(s); Ay += hi16f(s);
            }
            if (b) {
                Ax += b[2 * q];
                Ay += b[2 * q + 1];
            }
            if (relu) {
                Ax = fmaxf(Ax, 0.f);
                Ay = fmaxf(Ay, 0.f);
            }
            stw((u32*)out1 + (size_t)r * 8 + q, packbf(Ax, Ay));
            if (out2)
                stw((u32*)out2 + (size_t)r * 8 + q, packbf(Ax * d1, Ay * d1));
        }
        __syncthreads();   // WAR: protect eld before next group restage
    }
}

// ---- phase: GEMM1 (x @ W1 planes, row-normalize, tilde-scale planes 1..3) ----
__device__ void gemm1_phase(char* smem, const float* __restrict__ x,
                            const float* __restrict__ W1,
                            const float* __restrict__ dis,
                            u16* __restrict__ zb, int n, int nstride)
{
    float* As   = (float*)smem;
    float* Bs   = (float*)(smem + 33792);
    float* sums = (float*)(smem + 50176);
    const int t  = threadIdx.x;
    const int tx = t & 15;
    const int ty = t >> 4;
    const int c  = t & 15;
    const int g  = t >> 4;
    const int ntiles = (n + 127) >> 7;
    for (int tile = blockIdx.x; tile < ntiles; tile += MEGA_GRID) {
        const int block_row = tile << 7;
        float acc[8][4];
        #pragma unroll
        for (int i = 0; i < 8; ++i)
            #pragma unroll
            for (int j = 0; j < 4; ++j) acc[i][j] = 0.f;

        for (int kp = 0; kp < 2; ++kp) {
            #pragma unroll
            for (int i = 0; i < 8; ++i) {
                int row  = g + 16 * i;
                int grow = block_row + row;
                float v0 = 0.f, v1 = 0.f, v2 = 0.f, v3 = 0.f;
                if (grow < n) {
                    const float* xp = x + (long)grow * 128 + kp * 64 + c;
                    v0 = xp[0]; v1 = xp[16]; v2 = xp[32]; v3 = xp[48];
                }
                As[(c +  0) * 132 + row] = v0;
                As[(c + 16) * 132 + row] = v1;
                As[(c + 32) * 132 + row] = v2;
                As[(c + 48) * 132 + row] = v3;
                float red = (v0 + v1) + (v2 + v3);
                #pragma unroll
                for (int off = 8; off > 0; off >>= 1) red += __shfl_down(red, off, 16);
                if (c == 0) { if (kp == 0) sums[row] = red; else sums[row] += red; }
            }
            #pragma unroll
            for (int i2 = 0; i2 < 4; ++i2) {
                int kk = g + 16 * i2;
                int kglob = kp * 64 + kk;
                float4 wv = *(const float4*)(W1 + (c >> 2) * 2048 + kglob * 16 + 4 * (c & 3));
                *(float4*)(Bs + kk * 64 + 4 * c) = wv;
            }
            __syncthreads();
            #pragma unroll 4
            for (int kk = 0; kk < 64; ++kk) {
                float4 a0 = *(const float4*)(As + kk * 132 + 8 * ty);
                float4 a1 = *(const float4*)(As + kk * 132 + 8 * ty + 4);
                float4 bv = *(const float4*)(Bs + kk * 64 + 4 * tx);
                float ar[8] = {a0.x, a0.y, a0.z, a0.w, a1.x, a1.y, a1.z, a1.w};
                float br[4] = {bv.x, bv.y, bv.z, bv.w};
                #pragma unroll
                for (int i = 0; i < 8; ++i)
                    #pragma unroll
                    for (int j = 0; j < 4; ++j)
                        acc[i][j] += ar[i] * br[j];
            }
            __syncthreads();
        }
        int plane = tx >> 2;
        int oo4   = 4 * (tx & 3);
        #pragma unroll
        for (int i = 0; i < 8; ++i) {
            int row  = 8 * ty + i;
            int grow = block_row + row;
            if (grow < n) {
                float s = 1.0f / fmaxf(sums[row], 1e-8f);
                if (plane != 0) s *= dis[grow];          // tilde space for SpMM inputs
                u32* zp = (u32*)zb + (size_t)plane * (nstride >> 1) + (size_t)grow * 8 + (oo4 >> 1);
                stw(zp,     packbf(acc[i][0] * s, acc[i][1] * s));
                stw(zp + 1, packbf(acc[i][2] * s, acc[i][3] * s));
            }
        }
        __syncthreads();
    }
}

// ---- phase: GEMM2 (cat(planes 0..3) @ W2cat + b2 -> fp32 out) ----
// Staging reads are MALL-DIRECT (ldw): planes 0..3 were rewritten in place
// over Z0..Z3 whose stale cached copies may exist — MALL reads bypass them.
__device__ void gemm2_phase(char* smem, const u16* __restrict__ zb,
                            const float* __restrict__ W2,
                            const float* __restrict__ b2,
                            float* __restrict__ out, int n, int nstride)
{
    float* As = (float*)smem;
    float* Bs = (float*)(smem + 33792);
    const u32* zw = (const u32*)zb;
    const int nsw = nstride >> 1;     // u32 stride per plane
    const int t  = threadIdx.x;
    const int tx = t & 15;
    const int ty = t >> 4;
    const int c  = t & 15;
    const int g  = t >> 4;
    const int ntiles = (n + 127) >> 7;
    for (int tile = blockIdx.x; tile < ntiles; tile += MEGA_GRID) {
        const int block_row = tile << 7;
        float acc[8][4];
        #pragma unroll
        for (int i = 0; i < 8; ++i)
            #pragma unroll
            for (int j = 0; j < 4; ++j) acc[i][j] = 0.f;

        // staging: threads c=0..7 load pair c of planes 0,1; c=8..15 pair c-8 of planes 2,3
        #pragma unroll
        for (int i = 0; i < 8; ++i) {
            int row  = g + 16 * i;
            int grow = block_row + row;
            int pr   = c & 7;                       // pair index 0..7
            int pl   = (c < 8) ? 0 : 2;             // first plane this thread stages
            float l0 = 0.f, h0 = 0.f, l1 = 0.f, h1 = 0.f;
            if (grow < n) {
                u32 w0 = ldw(zw + (size_t)pl * nsw       + (size_t)grow * 8 + pr);
                u32 w1 = ldw(zw + (size_t)(pl + 1) * nsw + (size_t)grow * 8 + pr);
                l0 = lo16f(w0); h0 = hi16f(w0);
                l1 = lo16f(w1); h1 = hi16f(w1);
            }
            int col = pl * 16 + 2 * pr;
            As[(col +  0) * 132 + row] = l0;
            As[(col +  1) * 132 + row] = h0;
            As[(col + 16) * 132 + row] = l1;
            As[(col + 17) * 132 + row] = h1;
        }
        #pragma unroll
        for (int i2 = 0; i2 < 4; ++i2) {
            int j = g + 16 * i2;
            float4 wv = *(const float4*)(W2 + j * 64 + 4 * c);
            *(float4*)(Bs + j * 64 + 4 * c) = wv;
        }
        __syncthreads();
        #pragma unroll 4
        for (int kk = 0; kk < 64; ++kk) {
            float4 a0 = *(const float4*)(As + kk * 132 + 8 * ty);
            float4 a1 = *(const float4*)(As + kk * 132 + 8 * ty + 4);
            float4 bv = *(const float4*)(Bs + kk * 64 + 4 * tx);
            float ar[8] = {a0.x, a0.y, a0.z, a0.w, a1.x, a1.y, a1.z, a1.w};
            float br[4] = {bv.x, bv.y, bv.z, bv.w};
            #pragma unroll
            for (int i = 0; i < 8; ++i)
                #pragma unroll
                for (int j = 0; j < 4; ++j)
                    acc[i][j] += ar[i] * br[j];
        }
        float4 bias = *(const float4*)(b2 + 4 * tx);
        #pragma unroll
        for (int i = 0; i < 8; ++i) {
            int grow = block_row + 8 * ty + i;
            if (grow < n) {
                float4 o = make_float4(acc[i][0] + bias.x, acc[i][1] + bias.y,
                                       acc[i][2] + bias.z, acc[i][3] + bias.w);
                *(float4*)(out + (long)grow * 64 + 4 * tx) = o;   // flushed at kernel end
            }
        }
        __syncthreads();
    }
}

// ==================== the persistent mega-kernel ====================
// Single-assignment buffer plan (all writes MALL-direct; cached reads only
// hit addresses written once, before first read):
//   planes 0..3: Z0..Z3 (gemm1) -> later rewritten IN PLACE as H,G1,G2,G3
//                (read back only MALL-direct in gemm2)
//   plane 4: Y2 (hop1 out)   plane 5: Y1 (hop2 out)
//   plane 6: HT (hop3 out2)  plane 7: GT1 (hop4 out2)  plane 8: GT2 (hop5 out2)
__global__ __launch_bounds__(256, 3) void mega_kernel(
    const float* __restrict__ x, const int* __restrict__ srcp,
    const int* __restrict__ dstp,
    const float* __restrict__ W1, const float* __restrict__ b1,
    const float* __restrict__ W2, const float* __restrict__ b2,
    float* __restrict__ out,
    int* barr, int* cnt, int* rowptr, int* cursor, float* dis,
    u16* zb, u32* ecol, int n, int E, int nstride)
{
    __shared__ __align__(16) char smem[MEGA_LDS];
    const int gstride = MEGA_GRID * 256;

    // P1: in-degree count (cnt zeroed by preceding memset; MALL RMW)
    for (int e = blockIdx.x * 256 + threadIdx.x; e < E; e += gstride)
        __hip_atomic_fetch_add(cnt + dstp[e], 1, __ATOMIC_RELAXED, __HIP_MEMORY_SCOPE_AGENT);
    grid_bar(barr, 1);

    // P2: fused scan -> rowptr/cursor/dis
    scan_all(smem, cnt, rowptr, cursor, dis, n, E);
    grid_bar(barr, 2);

    // P3: scatter edges into CSR (atomic cursors) THEN gemm1 — independent
    for (int e = blockIdx.x * 256 + threadIdx.x; e < E; e += gstride) {
        int d = dstp[e];
        int p = aadd(cursor + d);
        stw(ecol + p, (u32)srcp[e]);
    }
    gemm1_phase(smem, x, W1, dis, zb, n, nstride);
    grid_bar(barr, 3);

    u16 *Z0 = zb,               *Z1 = zb + nstride,     *Z2 = zb + 2 * nstride,
        *Z3 = zb + 3 * nstride, *Y2 = zb + 4 * nstride, *Y1 = zb + 5 * nstride,
        *HT = zb + 6 * nstride, *GT1 = zb + 7 * nstride, *GT2 = zb + 8 * nstride;

    // L1 Horner (tilde space: scale1 = dis^2); every gather plane is fresh
    spmm_phase(smem, Z3, Z2, Y2, nullptr, rowptr, ecol, dis, nullptr, 0, 1, n);
    grid_bar(barr, 4);
    spmm_phase(smem, Y2, Z1, Y1, nullptr, rowptr, ecol, dis, nullptr, 0, 1, n);
    grid_bar(barr, 5);
    // H = relu(Z0 + dis*S + b1) written in place over Z0; HT = dis*H
    spmm_phase(smem, Y1, Z0, Z0, HT, rowptr, ecol, dis, b1, 1, 0, n);
    grid_bar(barr, 6);
    // L2 hops: Gk = dis*S (in place over Zk), tilde copy GTk = dis*Gk
    spmm_phase(smem, HT, nullptr, Z1, GT1, rowptr, ecol, dis, nullptr, 0, 0, n);
    grid_bar(barr, 7);
    spmm_phase(smem, GT1, nullptr, Z2, GT2, rowptr, ecol, dis, nullptr, 0, 0, n);
    grid_bar(barr, 8);
    spmm_phase(smem, GT2, nullptr, Z3, nullptr, rowptr, ecol, dis, nullptr, 0, 0, n);
    grid_bar(barr, 9);

    // P: GEMM2 -> out (MALL-direct staging reads)
    gemm2_phase(smem, zb, W2, b2, out, n, nstride);
}

// ================= fp32 fallback path (small workspace) =================
__global__ void deg_kernel(const int* __restrict__ dst, float* __restrict__ deg, int E) {
    int e = blockIdx.x * blockDim.x + threadIdx.x;
    if (e < E) atomicAdd(&deg[dst[e]], 1.0f);
}
__global__ void disf_kernel(float* __restrict__ deg, int n) {
    int i = blockIdx.x * blockDim.x + threadIdx.x;
    if (i < n) {
        float d = deg[i];
        deg[i] = (d > 0.0f) ? rsqrtf(d) : 0.0f;
    }
}
__global__ __launch_bounds__(256) void gemm1_f32_kernel(
    const float* __restrict__ x, const float* __restrict__ W1,
    float* __restrict__ z, int n, int nstride)
{
    __shared__ float As[64 * 132];
    __shared__ float Bs[64 * 64];
    __shared__ float sums[128];
    const int t  = threadIdx.x;
    const int tx = t & 15;
    const int ty = t >> 4;
    const int c  = t & 15;
    const int g  = t >> 4;
    const int block_row = blockIdx.x * 128;
    float acc[8][4];
    #pragma unroll
    for (int i = 0; i < 8; ++i)
        #pragma unroll
        for (int j = 0; j < 4; ++j) acc[i][j] = 0.f;
    for (int kp = 0; kp < 2; ++kp) {
        #pragma unroll
        for (int i = 0; i < 8; ++i) {
            int row  = g + 16 * i;
            int grow = block_row + row;
            float v0 = 0.f, v1 = 0.f, v2 = 0.f, v3 = 0.f;
            if (grow < n) {
                const float* xp = x + (long)grow * 128 + kp * 64 + c;
                v0 = xp[0]; v1 = xp[16]; v2 = xp[32]; v3 = xp[48];
            }
            As[(c +  0) * 132 + row] = v0;
            As[(c + 16) * 132 + row] = v1;
            As[(c + 32) * 132 + row] = v2;
            As[(c + 48) * 132 + row] = v3;
            float red = (v0 + v1) + (v2 + v3);
            #pragma unroll
            for (int off = 8; off > 0; off >>= 1) red += __shfl_down(red, off, 16);
            if (c == 0) { if (kp == 0) sums[row] = red; else sums[row] += red; }
        }
        #pragma unroll
        for (int i2 = 0; i2 < 4; ++i2) {
            int kk = g + 16 * i2;
            int kglob = kp * 64 + kk;
            float4 wv = *(const float4*)(W1 + (c >> 2) * 2048 + kglob * 16 + 4 * (c & 3));
            *(float4*)(Bs + kk * 64 + 4 * c) = wv;
        }
        __syncthreads();
        #pragma unroll 4
        for (int kk = 0; kk < 64; ++kk) {
            float4 a0 = *(const float4*)(As + kk * 132 + 8 * ty);
            float4 a1 = *(const float4*)(As + kk * 132 + 8 * ty + 4);
            float4 bv = *(const float4*)(Bs + kk * 64 + 4 * tx);
            float ar[8] = {a0.x, a0.y, a0.z, a0.w, a1.x, a1.y, a1.z, a1.w};
            float br[4] = {bv.x, bv.y, bv.z, bv.w};
            #pragma unroll
            for (int i = 0; i < 8; ++i)
                #pragma unroll
                for (int j = 0; j < 4; ++j)
                    acc[i][j] += ar[i] * br[j];
        }
        __syncthreads();
    }
    int plane = tx >> 2;
    int oo4   = 4 * (tx & 3);
    #pragma unroll
    for (int i = 0; i < 8; ++i) {
        int row  = 8 * ty + i;
        int grow = block_row + row;
        if (grow < n) {
            float s = 1.0f / fmaxf(sums[row], 1e-8f);
            float4 o = make_float4(acc[i][0] * s, acc[i][1] * s, acc[i][2] * s, acc[i][3] * s);
            *(float4*)(z + (long)plane * nstride + (long)grow * 16 + oo4) = o;
        }
    }
}
__global__ __launch_bounds__(256) void spmm_atomic_kernel(
    const float* __restrict__ in, float* __restrict__ out,
    const int* __restrict__ src, const int* __restrict__ dst,
    const float* __restrict__ dis, int E)
{
    int t = blockIdx.x * blockDim.x + threadIdx.x;
    int e = t >> 4, f = t & 15;
    if (e < E) {
        int s = src[e], d = dst[e];
        atomicAdd(&out[d * 16 + f], dis[s] * dis[d] * in[s * 16 + f]);
    }
}
__global__ void bias_relu_kernel(float* __restrict__ z0, const float* __restrict__ b, int total) {
    int i = blockIdx.x * blockDim.x + threadIdx.x;
    if (i < total) {
        float v = z0[i] + b[i & 15];
        z0[i] = v > 0.0f ? v : 0.0f;
    }
}
__global__ __launch_bounds__(256) void gemm2_f32_kernel(
    const float* __restrict__ z, const float* __restrict__ W2,
    const float* __restrict__ b2, float* __restrict__ out, int n, int nstride)
{
    __shared__ float As[64 * 132];
    __shared__ float Bs[64 * 64];
    const int t  = threadIdx.x;
    const int tx = t & 15;
    const int ty = t >> 4;
    const int c  = t & 15;
    const int g  = t >> 4;
    const int block_row = blockIdx.x * 128;
    float acc[8][4];
    #pragma unroll
    for (int i = 0; i < 8; ++i)
        #pragma unroll
        for (int j = 0; j < 4; ++j) acc[i][j] = 0.f;
    #pragma unroll
    for (int i = 0; i < 8; ++i) {
        int row  = g + 16 * i;
        int grow = block_row + row;
        float v0 = 0.f, v1 = 0.f, v2 = 0.f, v3 = 0.f;
        if (grow < n) {
            const float* zp = z + (long)grow * 16 + c;
            v0 = zp[0];
            v1 = zp[(long)nstride];
            v2 = zp[2 * (long)nstride];
            v3 = zp[3 * (long)nstride];
        }
        As[(c +  0) * 132 + row] = v0;
        As[(c + 16) * 132 + row] = v1;
        As[(c + 32) * 132 + row] = v2;
        As[(c + 48) * 132 + row] = v3;
    }
    #pragma unroll
    for (int i2 = 0; i2 < 4; ++i2) {
        int j = g + 16 * i2;
        float4 wv = *(const float4*)(W2 + j * 64 + 4 * c);
        *(float4*)(Bs + j * 64 + 4 * c) = wv;
    }
    __syncthreads();
    #pragma unroll 4
    for (int kk = 0; kk < 64; ++kk) {
        float4 a0 = *(const float4*)(As + kk * 132 + 8 * ty);
        float4 a1 = *(const float4*)(As + kk * 132 + 8 * ty + 4);
        float4 bv = *(const float4*)(Bs + kk * 64 + 4 * tx);
        float ar[8] = {a0.x, a0.y, a0.z, a0.w, a1.x, a1.y, a1.z, a1.w};
        float br[4] = {bv.x, bv.y, bv.z, bv.w};
        #pragma unroll
        for (int i = 0; i < 8; ++i)
            #pragma unroll
            for (int j = 0; j < 4; ++j)
                acc[i][j] += ar[i] * br[j];
    }
    float4 bias = *(const float4*)(b2 + 4 * tx);
    #pragma unroll
    for (int i = 0; i < 8; ++i) {
        int grow = block_row + 8 * ty + i;
        if (grow < n) {
            float4 o = make_float4(acc[i][0] + bias.x, acc[i][1] + bias.y,
                                   acc[i][2] + bias.z, acc[i][3] + bias.w);
            *(float4*)(out + (long)grow * 64 + 4 * tx) = o;
        }
    }
}

static inline size_t align16(size_t v) { return (v + 15) & ~(size_t)15; }

extern "C" void kernel_launch(void* const* d_in, const int* in_sizes, int n_in,
                              void* d_out, int out_size, void* d_ws, size_t ws_size,
                              hipStream_t stream) {
    const float* x   = (const float*)d_in[0];
    const int*   ei  = (const int*)d_in[1];
    const float* W1  = (const float*)d_in[2];
    const float* b1  = (const float*)d_in[3];
    const float* W2  = (const float*)d_in[4];
    const float* bb2 = (const float*)d_in[5];
    float* out = (float*)d_out;

    const int n  = in_sizes[0] / 128;   // 50000
    const int E  = in_sizes[1] / 2;     // 800000
    const int NS = n * 16;

    const int* srcp = ei;
    const int* dstp = ei + E;

    char* wsb = (char*)d_ws;
    // layout: barrier block (4096B) | cnt[n] | rowptr[n+1] | cursor[n] | dis[n]
    //         | zb[9*NS u16] | ecol[E u32]
    int*   barr   = (int*)wsb;
    int*   cnt    = (int*)(wsb + 4096);
    int*   rowptr = (int*)(wsb + 4096 + (size_t)4 * n);
    int*   cursor = (int*)(wsb + 4096 + (size_t)4 * (2 * n + 1));
    float* dis    = (float*)(wsb + 4096 + (size_t)4 * (3 * n + 1));
    size_t zoffb  = align16(4096 + (size_t)4 * (4 * n + 1));
    u16*   zb     = (u16*)(wsb + zoffb);
    size_t ecooff = align16(zoffb + (size_t)2 * 9 * NS);
    u32*   ecol   = (u32*)(wsb + ecooff);
    size_t need   = ecooff + (size_t)4 * E;

    if (ws_size >= need && n <= MEGA_GRID * 256) {
        // zero barrier block + degree counts, then one persistent kernel
        hipMemsetAsync(wsb, 0, 4096 + (size_t)4 * n, stream);
        mega_kernel<<<MEGA_GRID, 256, 0, stream>>>(
            x, srcp, dstp, W1, b1, W2, bb2, out,
            barr, cnt, rowptr, cursor, dis, zb, ecol, n, E, NS);
    } else {
        // ---------- fp32 atomic fallback ----------
        int gemm_blocks = (n + 127) / 128;
        float* ws = (float*)d_ws;
        float* dis2 = ws;
        size_t z2off = ((size_t)n + 3) & ~(size_t)3;
        float* z2 = ws + z2off;
        hipMemsetAsync(dis2, 0, n * sizeof(float), stream);
        deg_kernel<<<(E + 255) / 256, 256, 0, stream>>>(dstp, dis2, E);
        disf_kernel<<<(n + 255) / 256, 256, 0, stream>>>(dis2, n);
        gemm1_f32_kernel<<<gemm_blocks, 256, 0, stream>>>(x, W1, z2, n, NS);
        int sb = (16 * E + 255) / 256;
        spmm_atomic_kernel<<<sb, 256, 0, stream>>>(z2 + 3 * NS, z2 + 2 * NS, srcp, dstp, dis2, E);
        spmm_atomic_kernel<<<sb, 256, 0, stream>>>(z2 + 2 * NS, z2 + 1 * NS, srcp, dstp, dis2, E);
        spmm_atomic_kernel<<<sb, 256, 0, stream>>>(z2 + 1 * NS, z2,          srcp, dstp, dis2, E);
        bias_relu_kernel<<<(NS + 255) / 256, 256, 0, stream>>>(z2, b1, NS);
        hipMemsetAsync(z2 + NS, 0, (size_t)3 * NS * sizeof(float), stream);
        spmm_atomic_kernel<<<sb, 256, 0, stream>>>(z2,          z2 + NS,     srcp, dstp, dis2, E);
        spmm_atomic_kernel<<<sb, 256, 0, stream>>>(z2 + NS,     z2 + 2 * NS, srcp, dstp, dis2, E);
        spmm_atomic_kernel<<<sb, 256, 0, stream>>>(z2 + 2 * NS, z2 + 3 * NS, srcp, dstp, dis2, E);
        gemm2_f32_kernel<<<gemm_blocks, 256, 0, stream>>>(z2, W2, bb2, out, n, NS);
    }
}

// Round 6
// 344.527 us; speedup vs baseline: 2.0332x; 1.0187x over previous
//
#include <hip/hip_runtime.h>
#include <hip/hip_bf16.h>

typedef unsigned short u16;
typedef unsigned int u32;
typedef unsigned long long u64;

__device__ __forceinline__ float bf2f(u16 h) {
    return __uint_as_float(((u32)h) << 16);
}
__device__ __forceinline__ u16 f2bf(float f) {
    __hip_bfloat16 h = __float2bfloat16(f);   // RNE
    return *reinterpret_cast<u16*>(&h);
}

#define MEGA_GRID 768          // 256 CU x 3 blocks/CU (LDS-limited, see launch_bounds)
#define SPMM_ROWS 64           // 256 thr / 4 lanes-per-row
#define SPMM_LDSE 2048         // u32 entries (8KB); mean occupancy 1024 (Poisson, 32 sigma slack)
// smem layout: As[64*132]f @0 (33792B) | Bs[64*64]f @33792 (16384B) | sums[128]f @50176 (512B)
#define MEGA_LDS  50688
#define BAR_GROUPS 48
#define BAR_GSIZE  16          // 48*16 = 768

// ---------- MALL-direct accessors (agent-scope relaxed; bypass L1/L2) ----------
// ALL intermediate WRITES go through these (R3-proven fence-free-correct).
// Reads are plain cached EXCEPT gemm2 staging + barrier words: the dataflow is
// single-assignment w.r.t. cached reads, so no stale line can exist and NO
// cache maintenance op is ever needed.
__device__ __forceinline__ void stw(u32* p, u32 v) {
    __hip_atomic_store(p, v, __ATOMIC_RELAXED, __HIP_MEMORY_SCOPE_AGENT);
}
__device__ __forceinline__ void stl(u64* p, u64 v) {
    __hip_atomic_store(p, v, __ATOMIC_RELAXED, __HIP_MEMORY_SCOPE_AGENT);
}
__device__ __forceinline__ void sti(int* p, int v) {
    __hip_atomic_store(p, v, __ATOMIC_RELAXED, __HIP_MEMORY_SCOPE_AGENT);
}
__device__ __forceinline__ void stf(float* p, float v) {
    __hip_atomic_store(p, v, __ATOMIC_RELAXED, __HIP_MEMORY_SCOPE_AGENT);
}
__device__ __forceinline__ u32 ldw(const u32* p) {
    return __hip_atomic_load((u32*)p, __ATOMIC_RELAXED, __HIP_MEMORY_SCOPE_AGENT);
}
__device__ __forceinline__ int ldi(const int* p) {
    return __hip_atomic_load((int*)p, __ATOMIC_RELAXED, __HIP_MEMORY_SCOPE_AGENT);
}
__device__ __forceinline__ int aadd(int* p) {
    return __hip_atomic_fetch_add(p, 1, __ATOMIC_RELAXED, __HIP_MEMORY_SCOPE_AGENT);
}
__device__ __forceinline__ float lo16f(u32 w) { return __uint_as_float(w << 16); }
__device__ __forceinline__ float hi16f(u32 w) { return __uint_as_float(w & 0xffff0000u); }
__device__ __forceinline__ u32 packbf(float a, float b) {
    return (u32)f2bf(a) | ((u32)f2bf(b) << 16);
}

// ---- device-wide barrier: hierarchical arrival + separate release word ----
// 48 group counters (64B-strided) absorb 16 RMWs each in parallel; group
// finishers RMW a root counter; last group stores release=epoch; all blocks
// poll ONLY the read-only release line. Zero cache maintenance.
__device__ __forceinline__ void grid_bar(int* barr, int epoch) {
    __syncthreads();    // drains this block's vmem (all MALL stores acked)
    if (threadIdx.x == 0) {
        const int g = (int)blockIdx.x % BAR_GROUPS;
        int old = aadd(barr + g * 16);
        if (old == epoch * BAR_GSIZE - 1) {          // last of group this epoch
            int r = aadd(barr + 768);
            if (r == epoch * BAR_GROUPS - 1)         // last group
                sti(barr + 784, epoch);
        }
        while (ldi(barr + 784) < epoch)
            __builtin_amdgcn_s_sleep(16);
    }
    __syncthreads();
}

// ---- fused scan phase: each block redundantly base-sums cnt[0..s) (L2-hot),
// then scans its own chunk -> rowptr/cursor/dis. ONE phase, no partial array.
__device__ void scan_all(char* smem, const int* cnt, int* rowptr, int* cursor,
                         float* dis, int n, int E) {
    int* sc = (int*)smem;
    const int per = (n + MEGA_GRID - 1) / MEGA_GRID;    // <=256 (host guard)
    const int s = (int)blockIdx.x * per;
    const int t = threadIdx.x;
    // base = sum cnt[0..min(s,n))
    const int slim = min(s, n);
    int local = 0;
    for (int i = t; i < slim; i += 256) local += cnt[i];
    sc[t] = local;
    __syncthreads();
    #pragma unroll
    for (int off = 128; off > 0; off >>= 1) {
        if (t < off) sc[t] += sc[t + off];
        __syncthreads();
    }
    const int base = sc[0];
    __syncthreads();
    // exclusive scan of this block's chunk
    int i = s + t;
    bool act = (t < per && i < n);
    int v = act ? cnt[i] : 0;
    sc[t] = v;
    __syncthreads();
    #pragma unroll
    for (int off = 1; off < 256; off <<= 1) {
        int u = (t >= off) ? sc[t - off] : 0;
        __syncthreads();
        sc[t] += u;
        __syncthreads();
    }
    int excl = sc[t] - v;
    if (act) {
        int rp = base + excl;
        sti(rowptr + i, rp);
        sti(cursor + i, rp);
        stf(dis + i, (v > 0) ? rsqrtf((float)v) : 0.0f);
    }
    if (blockIdx.x == 0 && t == 0) sti(rowptr + n, E);
}

// ---- phase: CSR SpMM (tilde form), 4 lanes/row x uint2 gathers, unroll 8 ----
// MLP-oriented: per lane, 8 independent 8B gathers in flight (R5 was 4x4B with
// 8 lanes/row => 2x fewer loads AND 2x deeper pipeline). All reads cached
// (single-assignment dataflow); outputs MALL-direct 8B stores.
__device__ void spmm_phase(char* smem,
    const u16* __restrict__ in, const u16* __restrict__ addsrc,
    u16* __restrict__ out1, u16* __restrict__ out2,
    const int* __restrict__ rowptr, const u32* __restrict__ ecol,
    const float* __restrict__ dis, const float* __restrict__ b,
    int relu, int sq1, int n)
{
    u32* eld = (u32*)smem;
    const uint2* inq = (const uint2*)in;     // plane row = 4 uint2 (16 bf16)
    const int ngroups = (n + SPMM_ROWS - 1) / SPMM_ROWS;
    const int lr = threadIdx.x >> 2;          // local row 0..63
    const int q  = threadIdx.x & 3;           // feature quarter (4 bf16)
    for (int g = blockIdx.x; g < ngroups; g += MEGA_GRID) {
        const int r0 = g * SPMM_ROWS;
        const int rend = min(n, r0 + SPMM_ROWS);
        const int estart = rowptr[r0];
        const int eendb  = rowptr[rend];
        const int ne = eendb - estart;
        const bool lds_ok = (ne <= SPMM_LDSE);
        if (lds_ok) {
            for (int j = threadIdx.x; j < ne; j += 256)
                eld[j] = ecol[estart + j];
        }
        __syncthreads();
        const int r = r0 + lr;
        if (r < n) {
            int e0 = rowptr[r], e1 = rowptr[r + 1];
            float a0 = 0.f, a1 = 0.f, a2 = 0.f, a3 = 0.f;
            if (lds_ok) {
                int le = e0 - estart, le1 = e1 - estart;
                for (; le + 8 <= le1; le += 8) {
                    u32 s0 = eld[le+0], s1 = eld[le+1], s2 = eld[le+2], s3 = eld[le+3];
                    u32 s4 = eld[le+4], s5 = eld[le+5], s6 = eld[le+6], s7 = eld[le+7];
                    uint2 w0 = inq[(size_t)s0 * 4 + q];
                    uint2 w1 = inq[(size_t)s1 * 4 + q];
                    uint2 w2 = inq[(size_t)s2 * 4 + q];
                    uint2 w3 = inq[(size_t)s3 * 4 + q];
                    uint2 w4 = inq[(size_t)s4 * 4 + q];
                    uint2 w5 = inq[(size_t)s5 * 4 + q];
                    uint2 w6 = inq[(size_t)s6 * 4 + q];
                    uint2 w7 = inq[(size_t)s7 * 4 + q];
                    a0 += lo16f(w0.x); a1 += hi16f(w0.x); a2 += lo16f(w0.y); a3 += hi16f(w0.y);
                    a0 += lo16f(w1.x); a1 += hi16f(w1.x); a2 += lo16f(w1.y); a3 += hi16f(w1.y);
                    a0 += lo16f(w2.x); a1 += hi16f(w2.x); a2 += lo16f(w2.y); a3 += hi16f(w2.y);
                    a0 += lo16f(w3.x); a1 += hi16f(w3.x); a2 += lo16f(w3.y); a3 += hi16f(w3.y);
                    a0 += lo16f(w4.x); a1 += hi16f(w4.x); a2 += lo16f(w4.y); a3 += hi16f(w4.y);
                    a0 += lo16f(w5.x); a1 += hi16f(w5.x); a2 += lo16f(w5.y); a3 += hi16f(w5.y);
                    a0 += lo16f(w6.x); a1 += hi16f(w6.x); a2 += lo16f(w6.y); a3 += hi16f(w6.y);
                    a0 += lo16f(w7.x); a1 += hi16f(w7.x); a2 += lo16f(w7.y); a3 += hi16f(w7.y);
                }
                for (; le < le1; ++le) {
                    uint2 w0 = inq[(size_t)eld[le] * 4 + q];
                    a0 += lo16f(w0.x); a1 += hi16f(w0.x); a2 += lo16f(w0.y); a3 += hi16f(w0.y);
                }
            } else {
                int e = e0;
                for (; e + 8 <= e1; e += 8) {
                    u32 s0 = ecol[e+0], s1 = ecol[e+1], s2 = ecol[e+2], s3 = ecol[e+3];
                    u32 s4 = ecol[e+4], s5 = ecol[e+5], s6 = ecol[e+6], s7 = ecol[e+7];
                    uint2 w0 = inq[(size_t)s0 * 4 + q];
                    uint2 w1 = inq[(size_t)s1 * 4 + q];
                    uint2 w2 = inq[(size_t)s2 * 4 + q];
                    uint2 w3 = inq[(size_t)s3 * 4 + q];
                    uint2 w4 = inq[(size_t)s4 * 4 + q];
                    uint2 w5 = inq[(size_t)s5 * 4 + q];
                    uint2 w6 = inq[(size_t)s6 * 4 + q];
                    uint2 w7 = inq[(size_t)s7 * 4 + q];
                    a0 += lo16f(w0.x); a1 += hi16f(w0.x); a2 += lo16f(w0.y); a3 += hi16f(w0.y);
                    a0 += lo16f(w1.x); a1 += hi16f(w1.x); a2 += lo16f(w1.y); a3 += hi16f(w1.y);
                    a0 += lo16f(w2.x); a1 += hi16f(w2.x); a2 += lo16f(w2.y); a3 += hi16f(w2.y);
                    a0 += lo16f(w3.x); a1 += hi16f(w3.x); a2 += lo16f(w3.y); a3 += hi16f(w3.y);
                    a0 += lo16f(w4.x); a1 += hi16f(w4.x); a2 += lo16f(w4.y); a3 += hi16f(w4.y);
                    a0 += lo16f(w5.x); a1 += hi16f(w5.x); a2 += lo16f(w5.y); a3 += hi16f(w5.y);
                    a0 += lo16f(w6.x); a1 += hi16f(w6.x); a2 += lo16f(w6.y); a3 += hi16f(w6.y);
                    a0 += lo16f(w7.x); a1 += hi16f(w7.x); a2 += lo16f(w7.y); a3 += hi16f(w7.y);
                }
                for (; e < e1; ++e) {
                    uint2 w0 = inq[(size_t)ecol[e] * 4 + q];
                    a0 += lo16f(w0.x); a1 += hi16f(w0.x); a2 += lo16f(w0.y); a3 += hi16f(w0.y);
                }
            }
            float d1 = dis[r];
            float sc1 = sq1 ? d1 * d1 : d1;
            float A0 = a0 * sc1, A1 = a1 * sc1, A2 = a2 * sc1, A3 = a3 * sc1;
            if (addsrc) {
                uint2 s = ((const uint2*)addsrc)[(size_t)r * 4 + q];
                A0 += lo16f(s.x); A1 += hi16f(s.x); A2 += lo16f(s.y); A3 += hi16f(s.y);
            }
            if (b) {
                A0 += b[4 * q];     A1 += b[4 * q + 1];
                A2 += b[4 * q + 2]; A3 += b[4 * q + 3];
            }
            if (relu) {
                A0 = fmaxf(A0, 0.f); A1 = fmaxf(A1, 0.f);
                A2 = fmaxf(A2, 0.f); A3 = fmaxf(A3, 0.f);
            }
            u64 o = (u64)packbf(A0, A1) | ((u64)packbf(A2, A3) << 32);
            stl((u64*)out1 + (size_t)r * 4 + q, o);
            if (out2) {
                u64 o2 = (u64)packbf(A0 * d1, A1 * d1) | ((u64)packbf(A2 * d1, A3 * d1) << 32);
                stl((u64*)out2 + (size_t)r * 4 + q, o2);
            }
        }
        __syncthreads();   // WAR: protect eld before next group restage
    }
}

// ---- phase: GEMM1 (x @ W1 planes, row-normalize, tilde-scale planes 1..3) ----
__device__ void gemm1_phase(char* smem, const float* __restrict__ x,
                            const float* __restrict__ W1,
                            const float* __restrict__ dis,
                            u16* __restrict__ zb, int n, int nstride)
{
    float* As   = (float*)smem;
    float* Bs   = (float*)(smem + 33792);
    float* sums = (float*)(smem + 50176);
    const int t  = threadIdx.x;
    const int tx = t & 15;
    const int ty = t >> 4;
    const int c  = t & 15;
    const int g  = t >> 4;
    const int ntiles = (n + 127) >> 7;
    for (int tile = blockIdx.x; tile < ntiles; tile += MEGA_GRID) {
        const int block_row = tile << 7;
        float acc[8][4];
        #pragma unroll
        for (int i = 0; i < 8; ++i)
            #pragma unroll
            for (int j = 0; j < 4; ++j) acc[i][j] = 0.f;

        for (int kp = 0; kp < 2; ++kp) {
            #pragma unroll
            for (int i = 0; i < 8; ++i) {
                int row  = g + 16 * i;
                int grow = block_row + row;
                float v0 = 0.f, v1 = 0.f, v2 = 0.f, v3 = 0.f;
                if (grow < n) {
                    const float* xp = x + (long)grow * 128 + kp * 64 + c;
                    v0 = xp[0]; v1 = xp[16]; v2 = xp[32]; v3 = xp[48];
                }
                As[(c +  0) * 132 + row] = v0;
                As[(c + 16) * 132 + row] = v1;
                As[(c + 32) * 132 + row] = v2;
                As[(c + 48) * 132 + row] = v3;
                float red = (v0 + v1) + (v2 + v3);
                #pragma unroll
                for (int off = 8; off > 0; off >>= 1) red += __shfl_down(red, off, 16);
                if (c == 0) { if (kp == 0) sums[row] = red; else sums[row] += red; }
            }
            #pragma unroll
            for (int i2 = 0; i2 < 4; ++i2) {
                int kk = g + 16 * i2;
                int kglob = kp * 64 + kk;
                float4 wv = *(const float4*)(W1 + (c >> 2) * 2048 + kglob * 16 + 4 * (c & 3));
                *(float4*)(Bs + kk * 64 + 4 * c) = wv;
            }
            __syncthreads();
            #pragma unroll 4
            for (int kk = 0; kk < 64; ++kk) {
                float4 a0 = *(const float4*)(As + kk * 132 + 8 * ty);
                float4 a1 = *(const float4*)(As + kk * 132 + 8 * ty + 4);
                float4 bv = *(const float4*)(Bs + kk * 64 + 4 * tx);
                float ar[8] = {a0.x, a0.y, a0.z, a0.w, a1.x, a1.y, a1.z, a1.w};
                float br[4] = {bv.x, bv.y, bv.z, bv.w};
                #pragma unroll
                for (int i = 0; i < 8; ++i)
                    #pragma unroll
                    for (int j = 0; j < 4; ++j)
                        acc[i][j] += ar[i] * br[j];
            }
            __syncthreads();
        }
        int plane = tx >> 2;
        int oo4   = 4 * (tx & 3);
        #pragma unroll
        for (int i = 0; i < 8; ++i) {
            int row  = 8 * ty + i;
            int grow = block_row + row;
            if (grow < n) {
                float s = 1.0f / fmaxf(sums[row], 1e-8f);
                if (plane != 0) s *= dis[grow];          // tilde space for SpMM inputs
                u64* zp = (u64*)zb + (size_t)plane * (nstride >> 2) + (size_t)grow * 4 + (oo4 >> 2);
                u64 o = (u64)packbf(acc[i][0] * s, acc[i][1] * s)
                      | ((u64)packbf(acc[i][2] * s, acc[i][3] * s) << 32);
                stl(zp, o);
            }
        }
        __syncthreads();
    }
}

// ---- phase: GEMM2 (cat(planes 0..3) @ W2cat + b2 -> fp32 out) ----
// Staging reads are MALL-DIRECT (ldw): planes 0..3 were rewritten in place
// over Z0..Z3 whose stale cached copies may exist — MALL reads bypass them.
__device__ void gemm2_phase(char* smem, const u16* __restrict__ zb,
                            const float* __restrict__ W2,
                            const float* __restrict__ b2,
                            float* __restrict__ out, int n, int nstride)
{
    float* As = (float*)smem;
    float* Bs = (float*)(smem + 33792);
    const u32* zw = (const u32*)zb;
    const int nsw = nstride >> 1;     // u32 stride per plane
    const int t  = threadIdx.x;
    const int tx = t & 15;
    const int ty = t >> 4;
    const int c  = t & 15;
    const int g  = t >> 4;
    const int ntiles = (n + 127) >> 7;
    for (int tile = blockIdx.x; tile < ntiles; tile += MEGA_GRID) {
        const int block_row = tile << 7;
        float acc[8][4];
        #pragma unroll
        for (int i = 0; i < 8; ++i)
            #pragma unroll
            for (int j = 0; j < 4; ++j) acc[i][j] = 0.f;

        // staging: threads c=0..7 load pair c of planes 0,1; c=8..15 pair c-8 of planes 2,3
        #pragma unroll
        for (int i = 0; i < 8; ++i) {
            int row  = g + 16 * i;
            int grow = block_row + row;
            int pr   = c & 7;                       // pair index 0..7
            int pl   = (c < 8) ? 0 : 2;             // first plane this thread stages
            float l0 = 0.f, h0 = 0.f, l1 = 0.f, h1 = 0.f;
            if (grow < n) {
                u32 w0 = ldw(zw + (size_t)pl * nsw       + (size_t)grow * 8 + pr);
                u32 w1 = ldw(zw + (size_t)(pl + 1) * nsw + (size_t)grow * 8 + pr);
                l0 = lo16f(w0); h0 = hi16f(w0);
                l1 = lo16f(w1); h1 = hi16f(w1);
            }
            int col = pl * 16 + 2 * pr;
            As[(col +  0) * 132 + row] = l0;
            As[(col +  1) * 132 + row] = h0;
            As[(col + 16) * 132 + row] = l1;
            As[(col + 17) * 132 + row] = h1;
        }
        #pragma unroll
        for (int i2 = 0; i2 < 4; ++i2) {
            int j = g + 16 * i2;
            float4 wv = *(const float4*)(W2 + j * 64 + 4 * c);
            *(float4*)(Bs + j * 64 + 4 * c) = wv;
        }
        __syncthreads();
        #pragma unroll 4
        for (int kk = 0; kk < 64; ++kk) {
            float4 a0 = *(const float4*)(As + kk * 132 + 8 * ty);
            float4 a1 = *(const float4*)(As + kk * 132 + 8 * ty + 4);
            float4 bv = *(const float4*)(Bs + kk * 64 + 4 * tx);
            float ar[8] = {a0.x, a0.y, a0.z, a0.w, a1.x, a1.y, a1.z, a1.w};
            float br[4] = {bv.x, bv.y, bv.z, bv.w};
            #pragma unroll
            for (int i = 0; i < 8; ++i)
                #pragma unroll
                for (int j = 0; j < 4; ++j)
                    acc[i][j] += ar[i] * br[j];
        }
        float4 bias = *(const float4*)(b2 + 4 * tx);
        #pragma unroll
        for (int i = 0; i < 8; ++i) {
            int grow = block_row + 8 * ty + i;
            if (grow < n) {
                float4 o = make_float4(acc[i][0] + bias.x, acc[i][1] + bias.y,
                                       acc[i][2] + bias.z, acc[i][3] + bias.w);
                *(float4*)(out + (long)grow * 64 + 4 * tx) = o;   // flushed at kernel end
            }
        }
        __syncthreads();
    }
}

// ==================== the persistent mega-kernel ====================
// Single-assignment buffer plan (all writes MALL-direct; cached reads only
// hit addresses written once, before first read):
//   planes 0..3: Z0..Z3 (gemm1) -> later rewritten IN PLACE as H,G1,G2,G3
//                (read back only MALL-direct in gemm2)
//   plane 4: Y2 (hop1 out)   plane 5: Y1 (hop2 out)
//   plane 6: HT (hop3 out2)  plane 7: GT1 (hop4 out2)  plane 8: GT2 (hop5 out2)
__global__ __launch_bounds__(256, 3) void mega_kernel(
    const float* __restrict__ x, const int* __restrict__ srcp,
    const int* __restrict__ dstp,
    const float* __restrict__ W1, const float* __restrict__ b1,
    const float* __restrict__ W2, const float* __restrict__ b2,
    float* __restrict__ out,
    int* barr, int* cnt, int* rowptr, int* cursor, float* dis,
    u16* zb, u32* ecol, int n, int E, int nstride)
{
    __shared__ __align__(16) char smem[MEGA_LDS];
    const int gstride = MEGA_GRID * 256;

    // P1: in-degree count (cnt zeroed by preceding memset; MALL RMW)
    for (int e = blockIdx.x * 256 + threadIdx.x; e < E; e += gstride)
        __hip_atomic_fetch_add(cnt + dstp[e], 1, __ATOMIC_RELAXED, __HIP_MEMORY_SCOPE_AGENT);
    grid_bar(barr, 1);

    // P2: fused scan -> rowptr/cursor/dis
    scan_all(smem, cnt, rowptr, cursor, dis, n, E);
    grid_bar(barr, 2);

    // P3: scatter edges into CSR (atomic cursors) THEN gemm1 — independent
    for (int e = blockIdx.x * 256 + threadIdx.x; e < E; e += gstride) {
        int d = dstp[e];
        int p = aadd(cursor + d);
        stw(ecol + p, (u32)srcp[e]);
    }
    gemm1_phase(smem, x, W1, dis, zb, n, nstride);
    grid_bar(barr, 3);

    u16 *Z0 = zb,               *Z1 = zb + nstride,     *Z2 = zb + 2 * nstride,
        *Z3 = zb + 3 * nstride, *Y2 = zb + 4 * nstride, *Y1 = zb + 5 * nstride,
        *HT = zb + 6 * nstride, *GT1 = zb + 7 * nstride, *GT2 = zb + 8 * nstride;

    // L1 Horner (tilde space: scale1 = dis^2); every gather plane is fresh
    spmm_phase(smem, Z3, Z2, Y2, nullptr, rowptr, ecol, dis, nullptr, 0, 1, n);
    grid_bar(barr, 4);
    spmm_phase(smem, Y2, Z1, Y1, nullptr, rowptr, ecol, dis, nullptr, 0, 1, n);
    grid_bar(barr, 5);
    // H = relu(Z0 + dis*S + b1) written in place over Z0; HT = dis*H
    spmm_phase(smem, Y1, Z0, Z0, HT, rowptr, ecol, dis, b1, 1, 0, n);
    grid_bar(barr, 6);
    // L2 hops: Gk = dis*S (in place over Zk), tilde copy GTk = dis*Gk
    spmm_phase(smem, HT, nullptr, Z1, GT1, rowptr, ecol, dis, nullptr, 0, 0, n);
    grid_bar(barr, 7);
    spmm_phase(smem, GT1, nullptr, Z2, GT2, rowptr, ecol, dis, nullptr, 0, 0, n);
    grid_bar(barr, 8);
    spmm_phase(smem, GT2, nullptr, Z3, nullptr, rowptr, ecol, dis, nullptr, 0, 0, n);
    grid_bar(barr, 9);

    // P: GEMM2 -> out (MALL-direct staging reads)
    gemm2_phase(smem, zb, W2, b2, out, n, nstride);
}

// ================= fp32 fallback path (small workspace) =================
__global__ void deg_kernel(const int* __restrict__ dst, float* __restrict__ deg, int E) {
    int e = blockIdx.x * blockDim.x + threadIdx.x;
    if (e < E) atomicAdd(&deg[dst[e]], 1.0f);
}
__global__ void disf_kernel(float* __restrict__ deg, int n) {
    int i = blockIdx.x * blockDim.x + threadIdx.x;
    if (i < n) {
        float d = deg[i];
        deg[i] = (d > 0.0f) ? rsqrtf(d) : 0.0f;
    }
}
__global__ __launch_bounds__(256) void gemm1_f32_kernel(
    const float* __restrict__ x, const float* __restrict__ W1,
    float* __restrict__ z, int n, int nstride)
{
    __shared__ float As[64 * 132];
    __shared__ float Bs[64 * 64];
    __shared__ float sums[128];
    const int t  = threadIdx.x;
    const int tx = t & 15;
    const int ty = t >> 4;
    const int c  = t & 15;
    const int g  = t >> 4;
    const int block_row = blockIdx.x * 128;
    float acc[8][4];
    #pragma unroll
    for (int i = 0; i < 8; ++i)
        #pragma unroll
        for (int j = 0; j < 4; ++j) acc[i][j] = 0.f;
    for (int kp = 0; kp < 2; ++kp) {
        #pragma unroll
        for (int i = 0; i < 8; ++i) {
            int row  = g + 16 * i;
            int grow = block_row + row;
            float v0 = 0.f, v1 = 0.f, v2 = 0.f, v3 = 0.f;
            if (grow < n) {
                const float* xp = x + (long)grow * 128 + kp * 64 + c;
                v0 = xp[0]; v1 = xp[16]; v2 = xp[32]; v3 = xp[48];
            }
            As[(c +  0) * 132 + row] = v0;
            As[(c + 16) * 132 + row] = v1;
            As[(c + 32) * 132 + row] = v2;
            As[(c + 48) * 132 + row] = v3;
            float red = (v0 + v1) + (v2 + v3);
            #pragma unroll
            for (int off = 8; off > 0; off >>= 1) red += __shfl_down(red, off, 16);
            if (c == 0) { if (kp == 0) sums[row] = red; else sums[row] += red; }
        }
        #pragma unroll
        for (int i2 = 0; i2 < 4; ++i2) {
            int kk = g + 16 * i2;
            int kglob = kp * 64 + kk;
            float4 wv = *(const float4*)(W1 + (c >> 2) * 2048 + kglob * 16 + 4 * (c & 3));
            *(float4*)(Bs + kk * 64 + 4 * c) = wv;
        }
        __syncthreads();
        #pragma unroll 4
        for (int kk = 0; kk < 64; ++kk) {
            float4 a0 = *(const float4*)(As + kk * 132 + 8 * ty);
            float4 a1 = *(const float4*)(As + kk * 132 + 8 * ty + 4);
            float4 bv = *(const float4*)(Bs + kk * 64 + 4 * tx);
            float ar[8] = {a0.x, a0.y, a0.z, a0.w, a1.x, a1.y, a1.z, a1.w};
            float br[4] = {bv.x, bv.y, bv.z, bv.w};
            #pragma unroll
            for (int i = 0; i < 8; ++i)
                #pragma unroll
                for (int j = 0; j < 4; ++j)
                    acc[i][j] += ar[i] * br[j];
        }
        __syncthreads();
    }
    int plane = tx >> 2;
    int oo4   = 4 * (tx & 3);
    #pragma unroll
    for (int i = 0; i < 8; ++i) {
        int row  = 8 * ty + i;
        int grow = block_row + row;
        if (grow < n) {
            float s = 1.0f / fmaxf(sums[row], 1e-8f);
            float4 o = make_float4(acc[i][0] * s, acc[i][1] * s, acc[i][2] * s, acc[i][3] * s);
            *(float4*)(z + (long)plane * nstride + (long)grow * 16 + oo4) = o;
        }
    }
}
__global__ __launch_bounds__(256) void spmm_atomic_kernel(
    const float* __restrict__ in, float* __restrict__ out,
    const int* __restrict__ src, const int* __restrict__ dst,
    const float* __restrict__ dis, int E)
{
    int t = blockIdx.x * blockDim.x + threadIdx.x;
    int e = t >> 4, f = t & 15;
    if (e < E) {
        int s = src[e], d = dst[e];
        atomicAdd(&out[d * 16 + f], dis[s] * dis[d] * in[s * 16 + f]);
    }
}
__global__ void bias_relu_kernel(float* __restrict__ z0, const float* __restrict__ b, int total) {
    int i = blockIdx.x * blockDim.x + threadIdx.x;
    if (i < total) {
        float v = z0[i] + b[i & 15];
        z0[i] = v > 0.0f ? v : 0.0f;
    }
}
__global__ __launch_bounds__(256) void gemm2_f32_kernel(
    const float* __restrict__ z, const float* __restrict__ W2,
    const float* __restrict__ b2, float* __restrict__ out, int n, int nstride)
{
    __shared__ float As[64 * 132];
    __shared__ float Bs[64 * 64];
    const int t  = threadIdx.x;
    const int tx = t & 15;
    const int ty = t >> 4;
    const int c  = t & 15;
    const int g  = t >> 4;
    const int block_row = blockIdx.x * 128;
    float acc[8][4];
    #pragma unroll
    for (int i = 0; i < 8; ++i)
        #pragma unroll
        for (int j = 0; j < 4; ++j) acc[i][j] = 0.f;
    #pragma unroll
    for (int i = 0; i < 8; ++i) {
        int row  = g + 16 * i;
        int grow = block_row + row;
        float v0 = 0.f, v1 = 0.f, v2 = 0.f, v3 = 0.f;
        if (grow < n) {
            const float* zp = z + (long)grow * 16 + c;
            v0 = zp[0];
            v1 = zp[(long)nstride];
            v2 = zp[2 * (long)nstride];
            v3 = zp[3 * (long)nstride];
        }
        As[(c +  0) * 132 + row] = v0;
        As[(c + 16) * 132 + row] = v1;
        As[(c + 32) * 132 + row] = v2;
        As[(c + 48) * 132 + row] = v3;
    }
    #pragma unroll
    for (int i2 = 0; i2 < 4; ++i2) {
        int j = g + 16 * i2;
        float4 wv = *(const float4*)(W2 + j * 64 + 4 * c);
        *(float4*)(Bs + j * 64 + 4 * c) = wv;
    }
    __syncthreads();
    #pragma unroll 4
    for (int kk = 0; kk < 64; ++kk) {
        float4 a0 = *(const float4*)(As + kk * 132 + 8 * ty);
        float4 a1 = *(const float4*)(As + kk * 132 + 8 * ty + 4);
        float4 bv = *(const float4*)(Bs + kk * 64 + 4 * tx);
        float ar[8] = {a0.x, a0.y, a0.z, a0.w, a1.x, a1.y, a1.z, a1.w};
        float br[4] = {bv.x, bv.y, bv.z, bv.w};
        #pragma unroll
        for (int i = 0; i < 8; ++i)
            #pragma unroll
            for (int j = 0; j < 4; ++j)
                acc[i][j] += ar[i] * br[j];
    }
    float4 bias = *(const float4*)(b2 + 4 * tx);
    #pragma unroll
    for (int i = 0; i < 8; ++i) {
        int grow = block_row + 8 * ty + i;
        if (grow < n) {
            float4 o = make_float4(acc[i][0] + bias.x, acc[i][1] + bias.y,
                                   acc[i][2] + bias.z, acc[i][3] + bias.w);
            *(float4*)(out + (long)grow * 64 + 4 * tx) = o;
        }
    }
}

static inline size_t align16(size_t v) { return (v + 15) & ~(size_t)15; }

extern "C" void kernel_launch(void* const* d_in, const int* in_sizes, int n_in,
                              void* d_out, int out_size, void* d_ws, size_t ws_size,
                              hipStream_t stream) {
    const float* x   = (const float*)d_in[0];
    const int*   ei  = (const int*)d_in[1];
    const float* W1  = (const float*)d_in[2];
    const float* b1  = (const float*)d_in[3];
    const float* W2  = (const float*)d_in[4];
    const float* bb2 = (const float*)d_in[5];
    float* out = (float*)d_out;

    const int n  = in_sizes[0] / 128;   // 50000
    const int E  = in_sizes[1] / 2;     // 800000
    const int NS = n * 16;

    const int* srcp = ei;
    const int* dstp = ei + E;

    char* wsb = (char*)d_ws;
    // layout: barrier block (4096B) | cnt[n] | rowptr[n+1] | cursor[n] | dis[n]
    //         | zb[9*NS u16] | ecol[E u32]
    int*   barr   = (int*)wsb;
    int*   cnt    = (int*)(wsb + 4096);
    int*   rowptr = (int*)(wsb + 4096 + (size_t)4 * n);
    int*   cursor = (int*)(wsb + 4096 + (size_t)4 * (2 * n + 1));
    float* dis    = (float*)(wsb + 4096 + (size_t)4 * (3 * n + 1));
    size_t zoffb  = align16(4096 + (size_t)4 * (4 * n + 1));
    u16*   zb     = (u16*)(wsb + zoffb);
    size_t ecooff = align16(zoffb + (size_t)2 * 9 * NS);
    u32*   ecol   = (u32*)(wsb + ecooff);
    size_t need   = ecooff + (size_t)4 * E;

    if (ws_size >= need && n <= MEGA_GRID * 256) {
        // zero barrier block + degree counts, then one persistent kernel
        hipMemsetAsync(wsb, 0, 4096 + (size_t)4 * n, stream);
        mega_kernel<<<MEGA_GRID, 256, 0, stream>>>(
            x, srcp, dstp, W1, b1, W2, bb2, out,
            barr, cnt, rowptr, cursor, dis, zb, ecol, n, E, NS);
    } else {
        // ---------- fp32 atomic fallback ----------
        int gemm_blocks = (n + 127) / 128;
        float* ws = (float*)d_ws;
        float* dis2 = ws;
        size_t z2off = ((size_t)n + 3) & ~(size_t)3;
        float* z2 = ws + z2off;
        hipMemsetAsync(dis2, 0, n * sizeof(float), stream);
        deg_kernel<<<(E + 255) / 256, 256, 0, stream>>>(dstp, dis2, E);
        disf_kernel<<<(n + 255) / 256, 256, 0, stream>>>(dis2, n);
        gemm1_f32_kernel<<<gemm_blocks, 256, 0, stream>>>(x, W1, z2, n, NS);
        int sb = (16 * E + 255) / 256;
        spmm_atomic_kernel<<<sb, 256, 0, stream>>>(z2 + 3 * NS, z2 + 2 * NS, srcp, dstp, dis2, E);
        spmm_atomic_kernel<<<sb, 256, 0, stream>>>(z2 + 2 * NS, z2 + 1 * NS, srcp, dstp, dis2, E);
        spmm_atomic_kernel<<<sb, 256, 0, stream>>>(z2 + 1 * NS, z2,          srcp, dstp, dis2, E);
        bias_relu_kernel<<<(NS + 255) / 256, 256, 0, stream>>>(z2, b1, NS);
        hipMemsetAsync(z2 + NS, 0, (size_t)3 * NS * sizeof(float), stream);
        spmm_atomic_kernel<<<sb, 256, 0, stream>>>(z2,          z2 + NS,     srcp, dstp, dis2, E);
        spmm_atomic_kernel<<<sb, 256, 0, stream>>>(z2 + NS,     z2 + 2 * NS, srcp, dstp, dis2, E);
        spmm_atomic_kernel<<<sb, 256, 0, stream>>>(z2 + 2 * NS, z2 + 3 * NS, srcp, dstp, dis2, E);
        gemm2_f32_kernel<<<gemm_blocks, 256, 0, stream>>>(z2, W2, bb2, out, n, NS);
    }
}

// Round 7
// 301.535 us; speedup vs baseline: 2.3231x; 1.1426x over previous
//
#include <hip/hip_runtime.h>
#include <hip/hip_bf16.h>

typedef unsigned short u16;
typedef unsigned int u32;
typedef unsigned long long u64;

__device__ __forceinline__ float bf2f(u16 h) {
    return __uint_as_float(((u32)h) << 16);
}
__device__ __forceinline__ u16 f2bf(float f) {
    __hip_bfloat16 h = __float2bfloat16(f);   // RNE
    return *reinterpret_cast<u16*>(&h);
}

// ---------------- build-side (multi-kernel, proven R0 code) ----------------
#define BKT_SHIFT 7
#define BKT_SIZE  128
#define CHUNK     2048

// ---------------- compute-side persistent kernel ----------------
#define CGRID     1536         // 256 CU x 6 blocks/CU (25.6KB LDS, VGPR<=85)
#define SPMM_ROWS 32
#define SPMM_LDSE 2048
// smem: As[32*132]f @0 (16896B) | Bs[32*64]f @16896 (8192B) | sums[128]f @25088 (512B)
#define CLDS      25600
#define BAR_GROUPS 48
#define BAR_GSIZE  32          // 48*32 = 1536

// ---------- MALL-direct accessors (agent-scope relaxed; bypass L1/L2) ----------
__device__ __forceinline__ void stw(u32* p, u32 v) {
    __hip_atomic_store(p, v, __ATOMIC_RELAXED, __HIP_MEMORY_SCOPE_AGENT);
}
__device__ __forceinline__ void stl(u64* p, u64 v) {
    __hip_atomic_store(p, v, __ATOMIC_RELAXED, __HIP_MEMORY_SCOPE_AGENT);
}
__device__ __forceinline__ void sti(int* p, int v) {
    __hip_atomic_store(p, v, __ATOMIC_RELAXED, __HIP_MEMORY_SCOPE_AGENT);
}
__device__ __forceinline__ u32 ldw(const u32* p) {
    return __hip_atomic_load((u32*)p, __ATOMIC_RELAXED, __HIP_MEMORY_SCOPE_AGENT);
}
__device__ __forceinline__ int ldi(const int* p) {
    return __hip_atomic_load((int*)p, __ATOMIC_RELAXED, __HIP_MEMORY_SCOPE_AGENT);
}
__device__ __forceinline__ int aadd(int* p) {
    return __hip_atomic_fetch_add(p, 1, __ATOMIC_RELAXED, __HIP_MEMORY_SCOPE_AGENT);
}
__device__ __forceinline__ float lo16f(u32 w) { return __uint_as_float(w << 16); }
__device__ __forceinline__ float hi16f(u32 w) { return __uint_as_float(w & 0xffff0000u); }
__device__ __forceinline__ u32 packbf(float a, float b) {
    return (u32)f2bf(a) | ((u32)f2bf(b) << 16);
}

// ==================== CSR build kernels (R0, zero global atomics) ====================
__global__ __launch_bounds__(256) void hist_kernel(const int* __restrict__ dst,
                                                   int* __restrict__ hist,
                                                   int E, int nbA, int nbuck) {
    __shared__ int lh[512];
    for (int j = threadIdx.x; j < nbuck; j += 256) lh[j] = 0;
    __syncthreads();
    int base = blockIdx.x * CHUNK;
    int end  = min(E, base + CHUNK);
    for (int e = base + threadIdx.x; e < end; e += 256)
        atomicAdd(&lh[dst[e] >> BKT_SHIFT], 1);
    __syncthreads();
    for (int j = threadIdx.x; j < nbuck; j += 256)
        hist[j * nbA + blockIdx.x] = lh[j];       // bin-major for the scan
}
__global__ __launch_bounds__(256) void scanA_kernel(const int* __restrict__ in,
                                                    int* __restrict__ outp1,
                                                    int* __restrict__ bsum, int n) {
    __shared__ int lds[256];
    int i = blockIdx.x * 256 + threadIdx.x;
    int v = (i < n) ? in[i] : 0;
    lds[threadIdx.x] = v;
    __syncthreads();
    #pragma unroll
    for (int off = 1; off < 256; off <<= 1) {
        int t = (threadIdx.x >= off) ? lds[threadIdx.x - off] : 0;
        __syncthreads();
        lds[threadIdx.x] += t;
        __syncthreads();
    }
    if (i < n) outp1[i + 1] = lds[threadIdx.x];
    if (threadIdx.x == 255) bsum[blockIdx.x] = lds[255];
}
__global__ __launch_bounds__(1024) void scanB_kernel(int* __restrict__ bsum, int nb) {
    __shared__ int lds[1024];
    int t = threadIdx.x;
    int v = (t < nb) ? bsum[t] : 0;
    lds[t] = v;
    __syncthreads();
    #pragma unroll
    for (int off = 1; off < 1024; off <<= 1) {
        int u = (t >= off) ? lds[t - off] : 0;
        __syncthreads();
        lds[t] += u;
        __syncthreads();
    }
    if (t < nb) bsum[t] = lds[t] - v;
}
__global__ __launch_bounds__(256) void scanC_kernel(int* __restrict__ outp1,
                                                    const int* __restrict__ bsum, int n) {
    int i = blockIdx.x * 256 + threadIdx.x;
    if (i < n) outp1[i + 1] += bsum[blockIdx.x];
    if (i == 0) outp1[0] = 0;
}
__global__ __launch_bounds__(256) void bucket_scatter_kernel(
    const int* __restrict__ src, const int* __restrict__ dst,
    const int* __restrict__ hofs, int2* __restrict__ bucketed,
    int E, int nbA, int nbuck)
{
    __shared__ int lbase[512];
    __shared__ int lcnt[512];
    for (int j = threadIdx.x; j < nbuck; j += 256) {
        lbase[j] = hofs[j * nbA + blockIdx.x];
        lcnt[j] = 0;
    }
    __syncthreads();
    int base = blockIdx.x * CHUNK;
    int end  = min(E, base + CHUNK);
    for (int e = base + threadIdx.x; e < end; e += 256) {
        int d = dst[e];
        int b = d >> BKT_SHIFT;
        int r = atomicAdd(&lcnt[b], 1);
        bucketed[lbase[b] + r] = make_int2(src[e], d);
    }
}
__global__ __launch_bounds__(256) void csr_finalize_kernel(
    const int2* __restrict__ bucketed, const int* __restrict__ hofs,
    int* __restrict__ rowptr, float* __restrict__ dis,
    u32* __restrict__ ecol, int E, int nbA, int nbuck, int n)
{
    __shared__ int cnt[BKT_SIZE];
    __shared__ int run[BKT_SIZE];
    int b = blockIdx.x;
    int bstart = hofs[b * nbA];
    int bend   = (b == nbuck - 1) ? E : hofs[(b + 1) * nbA];
    for (int j = threadIdx.x; j < BKT_SIZE; j += 256) cnt[j] = 0;
    __syncthreads();
    for (int i = bstart + threadIdx.x; i < bend; i += 256)
        atomicAdd(&cnt[bucketed[i].y & (BKT_SIZE - 1)], 1);
    __syncthreads();
    if (threadIdx.x == 0) {
        int runacc = 0;
        for (int j = 0; j < BKT_SIZE; ++j) {
            int c = cnt[j];
            run[j] = runacc;
            runacc += c;
        }
    }
    __syncthreads();
    for (int j = threadIdx.x; j < BKT_SIZE; j += 256) {
        int d = b * BKT_SIZE + j;
        if (d < n) {
            rowptr[d] = bstart + run[j];
            int c = cnt[j];
            dis[d] = (c > 0) ? rsqrtf((float)c) : 0.0f;
        }
    }
    if (b == 0 && threadIdx.x == 0) rowptr[n] = E;
    __syncthreads();
    for (int i = bstart + threadIdx.x; i < bend; i += 256) {
        int2 p = bucketed[i];
        int j = p.y & (BKT_SIZE - 1);
        int r = atomicAdd(&run[j], 1);
        ecol[bstart + r] = (u32)p.x;
    }
}

// ==================== compute-side persistent kernel ====================

// hierarchical barrier: 48 group counters (64B-strided) + root + release word.
__device__ __forceinline__ void grid_bar(int* barr, int epoch) {
    __syncthreads();
    if (threadIdx.x == 0) {
        const int g = (int)blockIdx.x % BAR_GROUPS;
        int old = aadd(barr + g * 16);
        if (old == epoch * BAR_GSIZE - 1) {
            int r = aadd(barr + 768);
            if (r == epoch * BAR_GROUPS - 1)
                sti(barr + 784, epoch);
        }
        while (ldi(barr + 784) < epoch)
            __builtin_amdgcn_s_sleep(16);
    }
    __syncthreads();
}

// ---- GEMM1, K-chunked (4 x 32) for 25.6KB LDS ----
__device__ void gemm1_phase(char* smem, const float* __restrict__ x,
                            const float* __restrict__ W1,
                            const float* __restrict__ dis,
                            u16* __restrict__ zb, int n, int nstride)
{
    float* As   = (float*)smem;              // [32][132]
    float* Bs   = (float*)(smem + 16896);    // [32][64]
    float* sums = (float*)(smem + 25088);    // [128]
    const int t  = threadIdx.x;
    const int tx = t & 15;
    const int ty = t >> 4;
    const int c  = t & 15;
    const int g  = t >> 4;
    const int ntiles = (n + 127) >> 7;
    for (int tile = blockIdx.x; tile < ntiles; tile += CGRID) {
        const int block_row = tile << 7;
        float acc[8][4];
        #pragma unroll
        for (int i = 0; i < 8; ++i)
            #pragma unroll
            for (int j = 0; j < 4; ++j) acc[i][j] = 0.f;

        for (int kc = 0; kc < 4; ++kc) {
            #pragma unroll
            for (int i = 0; i < 8; ++i) {
                int row  = g + 16 * i;
                int grow = block_row + row;
                float v0 = 0.f, v1 = 0.f;
                if (grow < n) {
                    const float* xp = x + (long)grow * 128 + kc * 32 + c;
                    v0 = xp[0]; v1 = xp[16];
                }
                As[(c +  0) * 132 + row] = v0;
                As[(c + 16) * 132 + row] = v1;
                float red = v0 + v1;
                #pragma unroll
                for (int off = 8; off > 0; off >>= 1) red += __shfl_down(red, off, 16);
                if (c == 0) { if (kc == 0) sums[row] = red; else sums[row] += red; }
            }
            #pragma unroll
            for (int i2 = 0; i2 < 2; ++i2) {
                int kk = g + 16 * i2;
                int kglob = kc * 32 + kk;
                float4 wv = *(const float4*)(W1 + (c >> 2) * 2048 + kglob * 16 + 4 * (c & 3));
                *(float4*)(Bs + kk * 64 + 4 * c) = wv;
            }
            __syncthreads();
            #pragma unroll 4
            for (int kk = 0; kk < 32; ++kk) {
                float4 a0 = *(const float4*)(As + kk * 132 + 8 * ty);
                float4 a1 = *(const float4*)(As + kk * 132 + 8 * ty + 4);
                float4 bv = *(const float4*)(Bs + kk * 64 + 4 * tx);
                float ar[8] = {a0.x, a0.y, a0.z, a0.w, a1.x, a1.y, a1.z, a1.w};
                float br[4] = {bv.x, bv.y, bv.z, bv.w};
                #pragma unroll
                for (int i = 0; i < 8; ++i)
                    #pragma unroll
                    for (int j = 0; j < 4; ++j)
                        acc[i][j] += ar[i] * br[j];
            }
            __syncthreads();
        }
        int plane = tx >> 2;
        int oo4   = 4 * (tx & 3);
        #pragma unroll
        for (int i = 0; i < 8; ++i) {
            int row  = 8 * ty + i;
            int grow = block_row + row;
            if (grow < n) {
                float s = 1.0f / fmaxf(sums[row], 1e-8f);
                if (plane != 0) s *= dis[grow];          // tilde space for SpMM inputs
                u64* zp = (u64*)zb + (size_t)plane * (nstride >> 2) + (size_t)grow * 4 + (oo4 >> 2);
                u64 o = (u64)packbf(acc[i][0] * s, acc[i][1] * s)
                      | ((u64)packbf(acc[i][2] * s, acc[i][3] * s) << 32);
                stl(zp, o);
            }
        }
        __syncthreads();
    }
}

// ---- CSR SpMM (tilde form), 32 rows x 8 lanes, u32 gathers, unroll 8 ----
// Reads cached (single-assignment dataflow); outputs MALL-direct.
__device__ void spmm_phase(char* smem,
    const u16* __restrict__ in, const u16* __restrict__ addsrc,
    u16* __restrict__ out1, u16* __restrict__ out2,
    const int* __restrict__ rowptr, const u32* __restrict__ ecol,
    const float* __restrict__ dis, const float* __restrict__ b,
    int relu, int sq1, int n)
{
    u32* eld = (u32*)smem;
    const u32* inw = (const u32*)in;     // plane row = 8 u32 (16 bf16)
    const int ngroups = (n + SPMM_ROWS - 1) / SPMM_ROWS;
    const int lr = threadIdx.x >> 3;
    const int q  = threadIdx.x & 7;
    for (int g = blockIdx.x; g < ngroups; g += CGRID) {
        const int r0 = g * SPMM_ROWS;
        const int rend = min(n, r0 + SPMM_ROWS);
        const int estart = rowptr[r0];
        const int eendb  = rowptr[rend];
        const int ne = eendb - estart;
        const bool lds_ok = (ne <= SPMM_LDSE);
        if (lds_ok) {
            for (int j = threadIdx.x; j < ne; j += 256)
                eld[j] = ecol[estart + j];
        }
        __syncthreads();
        const int r = r0 + lr;
        if (r < n) {
            int e0 = rowptr[r], e1 = rowptr[r + 1];
            float ax0=0,ay0=0, ax1=0,ay1=0, ax2=0,ay2=0, ax3=0,ay3=0;
            if (lds_ok) {
                int le = e0 - estart, le1 = e1 - estart;
                for (; le + 8 <= le1; le += 8) {
                    u32 s0 = eld[le+0], s1 = eld[le+1], s2 = eld[le+2], s3 = eld[le+3];
                    u32 s4 = eld[le+4], s5 = eld[le+5], s6 = eld[le+6], s7 = eld[le+7];
                    u32 w0 = inw[(size_t)s0 * 8 + q];
                    u32 w1 = inw[(size_t)s1 * 8 + q];
                    u32 w2 = inw[(size_t)s2 * 8 + q];
                    u32 w3 = inw[(size_t)s3 * 8 + q];
                    u32 w4 = inw[(size_t)s4 * 8 + q];
                    u32 w5 = inw[(size_t)s5 * 8 + q];
                    u32 w6 = inw[(size_t)s6 * 8 + q];
                    u32 w7 = inw[(size_t)s7 * 8 + q];
                    ax0 += lo16f(w0); ay0 += hi16f(w0);
                    ax1 += lo16f(w1); ay1 += hi16f(w1);
                    ax2 += lo16f(w2); ay2 += hi16f(w2);
                    ax3 += lo16f(w3); ay3 += hi16f(w3);
                    ax0 += lo16f(w4); ay0 += hi16f(w4);
                    ax1 += lo16f(w5); ay1 += hi16f(w5);
                    ax2 += lo16f(w6); ay2 += hi16f(w6);
                    ax3 += lo16f(w7); ay3 += hi16f(w7);
                }
                for (; le < le1; ++le) {
                    u32 w0 = inw[(size_t)eld[le] * 8 + q];
                    ax0 += lo16f(w0); ay0 += hi16f(w0);
                }
            } else {
                int e = e0;
                for (; e + 4 <= e1; e += 4) {
                    u32 s0 = ecol[e], s1 = ecol[e+1], s2 = ecol[e+2], s3 = ecol[e+3];
                    u32 w0 = inw[(size_t)s0 * 8 + q];
                    u32 w1 = inw[(size_t)s1 * 8 + q];
                    u32 w2 = inw[(size_t)s2 * 8 + q];
                    u32 w3 = inw[(size_t)s3 * 8 + q];
                    ax0 += lo16f(w0); ay0 += hi16f(w0);
                    ax1 += lo16f(w1); ay1 += hi16f(w1);
                    ax2 += lo16f(w2); ay2 += hi16f(w2);
                    ax3 += lo16f(w3); ay3 += hi16f(w3);
                }
                for (; e < e1; ++e) {
                    u32 w0 = inw[(size_t)ecol[e] * 8 + q];
                    ax0 += lo16f(w0); ay0 += hi16f(w0);
                }
            }
            float Sx = (ax0 + ax1) + (ax2 + ax3);
            float Sy = (ay0 + ay1) + (ay2 + ay3);
            float d1 = dis[r];
            float sc1 = sq1 ? d1 * d1 : d1;
            float Ax = Sx * sc1, Ay = Sy * sc1;
            if (addsrc) {
                u32 s = ((const u32*)addsrc)[(size_t)r * 8 + q];
                Ax += lo16f(s); Ay += hi16f(s);
            }
            if (b) {
                Ax += b[2 * q];
                Ay += b[2 * q + 1];
            }
            if (relu) {
                Ax = fmaxf(Ax, 0.f);
                Ay = fmaxf(Ay, 0.f);
            }
            stw((u32*)out1 + (size_t)r * 8 + q, packbf(Ax, Ay));
            if (out2)
                stw((u32*)out2 + (size_t)r * 8 + q, packbf(Ax * d1, Ay * d1));
        }
        __syncthreads();   // WAR: protect eld before next group restage
    }
}

// ---- GEMM2, K-chunked (2 x 32 = 2 planes/chunk); staging reads MALL-direct ----
__device__ void gemm2_phase(char* smem, const u16* __restrict__ zb,
                            const float* __restrict__ W2,
                            const float* __restrict__ b2,
                            float* __restrict__ out, int n, int nstride)
{
    float* As = (float*)smem;               // [32][132]
    float* Bs = (float*)(smem + 16896);     // [32][64]
    const u32* zw = (const u32*)zb;
    const int nsw = nstride >> 1;           // u32 stride per plane
    const int t  = threadIdx.x;
    const int tx = t & 15;
    const int ty = t >> 4;
    const int c  = t & 15;
    const int g  = t >> 4;
    const int ntiles = (n + 127) >> 7;
    for (int tile = blockIdx.x; tile < ntiles; tile += CGRID) {
        const int block_row = tile << 7;
        float acc[8][4];
        #pragma unroll
        for (int i = 0; i < 8; ++i)
            #pragma unroll
            for (int j = 0; j < 4; ++j) acc[i][j] = 0.f;

        for (int cc = 0; cc < 2; ++cc) {     // chunk = 2 planes = 32 cols
            #pragma unroll
            for (int i = 0; i < 8; ++i) {
                int row  = g + 16 * i;
                int grow = block_row + row;
                int pr     = c & 7;          // bf16-pair index within plane
                int pl_off = c >> 3;         // 0 or 1 within chunk
                int plane  = cc * 2 + pl_off;
                float lo = 0.f, hi = 0.f;
                if (grow < n) {
                    u32 w = ldw(zw + (size_t)plane * nsw + (size_t)grow * 8 + pr);
                    lo = lo16f(w); hi = hi16f(w);
                }
                int col = pl_off * 16 + 2 * pr;
                As[(col + 0) * 132 + row] = lo;
                As[(col + 1) * 132 + row] = hi;
            }
            #pragma unroll
            for (int i2 = 0; i2 < 2; ++i2) {
                int kk = g + 16 * i2;
                int kglob = cc * 32 + kk;
                float4 wv = *(const float4*)(W2 + kglob * 64 + 4 * c);
                *(float4*)(Bs + kk * 64 + 4 * c) = wv;
            }
            __syncthreads();
            #pragma unroll 4
            for (int kk = 0; kk < 32; ++kk) {
                float4 a0 = *(const float4*)(As + kk * 132 + 8 * ty);
                float4 a1 = *(const float4*)(As + kk * 132 + 8 * ty + 4);
                float4 bv = *(const float4*)(Bs + kk * 64 + 4 * tx);
                float ar[8] = {a0.x, a0.y, a0.z, a0.w, a1.x, a1.y, a1.z, a1.w};
                float br[4] = {bv.x, bv.y, bv.z, bv.w};
                #pragma unroll
                for (int i = 0; i < 8; ++i)
                    #pragma unroll
                    for (int j = 0; j < 4; ++j)
                        acc[i][j] += ar[i] * br[j];
            }
            __syncthreads();
        }
        float4 bias = *(const float4*)(b2 + 4 * tx);
        #pragma unroll
        for (int i = 0; i < 8; ++i) {
            int grow = block_row + 8 * ty + i;
            if (grow < n) {
                float4 o = make_float4(acc[i][0] + bias.x, acc[i][1] + bias.y,
                                       acc[i][2] + bias.z, acc[i][3] + bias.w);
                *(float4*)(out + (long)grow * 64 + 4 * tx) = o;   // flushed at kernel end
            }
        }
        __syncthreads();
    }
}

// Plane plan (single-assignment w.r.t. cached reads, as in R5/R6):
//   planes 0..3: Z0..Z3 (gemm1, MALL) -> rewritten in place as H,G1,G2,G3
//                (read back only MALL-direct in gemm2)
//   plane 4: Y2  plane 5: Y1  plane 6: HT  plane 7: GT1  plane 8: GT2
__global__ __launch_bounds__(256, 6) void compute_kernel(
    const float* __restrict__ x,
    const float* __restrict__ W1, const float* __restrict__ b1,
    const float* __restrict__ W2, const float* __restrict__ b2,
    float* __restrict__ out,
    int* barr, const int* __restrict__ rowptr, const u32* __restrict__ ecol,
    const float* __restrict__ dis, u16* zb, int n, int nstride)
{
    __shared__ __align__(16) char smem[CLDS];

    gemm1_phase(smem, x, W1, dis, zb, n, nstride);
    grid_bar(barr, 1);

    u16 *Z0 = zb,               *Z1 = zb + nstride,     *Z2 = zb + 2 * nstride,
        *Z3 = zb + 3 * nstride, *Y2 = zb + 4 * nstride, *Y1 = zb + 5 * nstride,
        *HT = zb + 6 * nstride, *GT1 = zb + 7 * nstride, *GT2 = zb + 8 * nstride;

    // L1 Horner (tilde space: scale1 = dis^2); every gather plane is fresh
    spmm_phase(smem, Z3, Z2, Y2, nullptr, rowptr, ecol, dis, nullptr, 0, 1, n);
    grid_bar(barr, 2);
    spmm_phase(smem, Y2, Z1, Y1, nullptr, rowptr, ecol, dis, nullptr, 0, 1, n);
    grid_bar(barr, 3);
    // H = relu(Z0 + dis*S + b1) in place over Z0; HT = dis*H
    spmm_phase(smem, Y1, Z0, Z0, HT, rowptr, ecol, dis, b1, 1, 0, n);
    grid_bar(barr, 4);
    // L2 hops: Gk = dis*S (in place over Zk), tilde copy GTk = dis*Gk
    spmm_phase(smem, HT, nullptr, Z1, GT1, rowptr, ecol, dis, nullptr, 0, 0, n);
    grid_bar(barr, 5);
    spmm_phase(smem, GT1, nullptr, Z2, GT2, rowptr, ecol, dis, nullptr, 0, 0, n);
    grid_bar(barr, 6);
    spmm_phase(smem, GT2, nullptr, Z3, nullptr, rowptr, ecol, dis, nullptr, 0, 0, n);
    grid_bar(barr, 7);

    gemm2_phase(smem, zb, W2, b2, out, n, nstride);
}

// ================= fp32 fallback path (small workspace) =================
__global__ void deg_kernel(const int* __restrict__ dst, float* __restrict__ deg, int E) {
    int e = blockIdx.x * blockDim.x + threadIdx.x;
    if (e < E) atomicAdd(&deg[dst[e]], 1.0f);
}
__global__ void disf_kernel(float* __restrict__ deg, int n) {
    int i = blockIdx.x * blockDim.x + threadIdx.x;
    if (i < n) {
        float d = deg[i];
        deg[i] = (d > 0.0f) ? rsqrtf(d) : 0.0f;
    }
}
__global__ __launch_bounds__(256) void gemm1_f32_kernel(
    const float* __restrict__ x, const float* __restrict__ W1,
    float* __restrict__ z, int n, int nstride)
{
    __shared__ float As[64 * 132];
    __shared__ float Bs[64 * 64];
    __shared__ float sums[128];
    const int t  = threadIdx.x;
    const int tx = t & 15;
    const int ty = t >> 4;
    const int c  = t & 15;
    const int g  = t >> 4;
    const int block_row = blockIdx.x * 128;
    float acc[8][4];
    #pragma unroll
    for (int i = 0; i < 8; ++i)
        #pragma unroll
        for (int j = 0; j < 4; ++j) acc[i][j] = 0.f;
    for (int kp = 0; kp < 2; ++kp) {
        #pragma unroll
        for (int i = 0; i < 8; ++i) {
            int row  = g + 16 * i;
            int grow = block_row + row;
            float v0 = 0.f, v1 = 0.f, v2 = 0.f, v3 = 0.f;
            if (grow < n) {
                const float* xp = x + (long)grow * 128 + kp * 64 + c;
                v0 = xp[0]; v1 = xp[16]; v2 = xp[32]; v3 = xp[48];
            }
            As[(c +  0) * 132 + row] = v0;
            As[(c + 16) * 132 + row] = v1;
            As[(c + 32) * 132 + row] = v2;
            As[(c + 48) * 132 + row] = v3;
            float red = (v0 + v1) + (v2 + v3);
            #pragma unroll
            for (int off = 8; off > 0; off >>= 1) red += __shfl_down(red, off, 16);
            if (c == 0) { if (kp == 0) sums[row] = red; else sums[row] += red; }
        }
        #pragma unroll
        for (int i2 = 0; i2 < 4; ++i2) {
            int kk = g + 16 * i2;
            int kglob = kp * 64 + kk;
            float4 wv = *(const float4*)(W1 + (c >> 2) * 2048 + kglob * 16 + 4 * (c & 3));
            *(float4*)(Bs + kk * 64 + 4 * c) = wv;
        }
        __syncthreads();
        #pragma unroll 4
        for (int kk = 0; kk < 64; ++kk) {
            float4 a0 = *(const float4*)(As + kk * 132 + 8 * ty);
            float4 a1 = *(const float4*)(As + kk * 132 + 8 * ty + 4);
            float4 bv = *(const float4*)(Bs + kk * 64 + 4 * tx);
            float ar[8] = {a0.x, a0.y, a0.z, a0.w, a1.x, a1.y, a1.z, a1.w};
            float br[4] = {bv.x, bv.y, bv.z, bv.w};
            #pragma unroll
            for (int i = 0; i < 8; ++i)
                #pragma unroll
                for (int j = 0; j < 4; ++j)
                    acc[i][j] += ar[i] * br[j];
        }
        __syncthreads();
    }
    int plane = tx >> 2;
    int oo4   = 4 * (tx & 3);
    #pragma unroll
    for (int i = 0; i < 8; ++i) {
        int row  = 8 * ty + i;
        int grow = block_row + row;
        if (grow < n) {
            float s = 1.0f / fmaxf(sums[row], 1e-8f);
            float4 o = make_float4(acc[i][0] * s, acc[i][1] * s, acc[i][2] * s, acc[i][3] * s);
            *(float4*)(z + (long)plane * nstride + (long)grow * 16 + oo4) = o;
        }
    }
}
__global__ __launch_bounds__(256) void spmm_atomic_kernel(
    const float* __restrict__ in, float* __restrict__ out,
    const int* __restrict__ src, const int* __restrict__ dst,
    const float* __restrict__ dis, int E)
{
    int t = blockIdx.x * blockDim.x + threadIdx.x;
    int e = t >> 4, f = t & 15;
    if (e < E) {
        int s = src[e], d = dst[e];
        atomicAdd(&out[d * 16 + f], dis[s] * dis[d] * in[s * 16 + f]);
    }
}
__global__ void bias_relu_kernel(float* __restrict__ z0, const float* __restrict__ b, int total) {
    int i = blockIdx.x * blockDim.x + threadIdx.x;
    if (i < total) {
        float v = z0[i] + b[i & 15];
        z0[i] = v > 0.0f ? v : 0.0f;
    }
}
__global__ __launch_bounds__(256) void gemm2_f32_kernel(
    const float* __restrict__ z, const float* __restrict__ W2,
    const float* __restrict__ b2, float* __restrict__ out, int n, int nstride)
{
    __shared__ float As[64 * 132];
    __shared__ float Bs[64 * 64];
    const int t  = threadIdx.x;
    const int tx = t & 15;
    const int ty = t >> 4;
    const int c  = t & 15;
    const int g  = t >> 4;
    const int block_row = blockIdx.x * 128;
    float acc[8][4];
    #pragma unroll
    for (int i = 0; i < 8; ++i)
        #pragma unroll
        for (int j = 0; j < 4; ++j) acc[i][j] = 0.f;
    #pragma unroll
    for (int i = 0; i < 8; ++i) {
        int row  = g + 16 * i;
        int grow = block_row + row;
        float v0 = 0.f, v1 = 0.f, v2 = 0.f, v3 = 0.f;
        if (grow < n) {
            const float* zp = z + (long)grow * 16 + c;
            v0 = zp[0];
            v1 = zp[(long)nstride];
            v2 = zp[2 * (long)nstride];
            v3 = zp[3 * (long)nstride];
        }
        As[(c +  0) * 132 + row] = v0;
        As[(c + 16) * 132 + row] = v1;
        As[(c + 32) * 132 + row] = v2;
        As[(c + 48) * 132 + row] = v3;
    }
    #pragma unroll
    for (int i2 = 0; i2 < 4; ++i2) {
        int j = g + 16 * i2;
        float4 wv = *(const float4*)(W2 + j * 64 + 4 * c);
        *(float4*)(Bs + j * 64 + 4 * c) = wv;
    }
    __syncthreads();
    #pragma unroll 4
    for (int kk = 0; kk < 64; ++kk) {
        float4 a0 = *(const float4*)(As + kk * 132 + 8 * ty);
        float4 a1 = *(const float4*)(As + kk * 132 + 8 * ty + 4);
        float4 bv = *(const float4*)(Bs + kk * 64 + 4 * tx);
        float ar[8] = {a0.x, a0.y, a0.z, a0.w, a1.x, a1.y, a1.z, a1.w};
        float br[4] = {bv.x, bv.y, bv.z, bv.w};
        #pragma unroll
        for (int i = 0; i < 8; ++i)
            #pragma unroll
            for (int j = 0; j < 4; ++j)
                acc[i][j] += ar[i] * br[j];
    }
    float4 bias = *(const float4*)(b2 + 4 * tx);
    #pragma unroll
    for (int i = 0; i < 8; ++i) {
        int grow = block_row + 8 * ty + i;
        if (grow < n) {
            float4 o = make_float4(acc[i][0] + bias.x, acc[i][1] + bias.y,
                                   acc[i][2] + bias.z, acc[i][3] + bias.w);
            *(float4*)(out + (long)grow * 64 + 4 * tx) = o;
        }
    }
}

static inline size_t align16(size_t v) { return (v + 15) & ~(size_t)15; }

extern "C" void kernel_launch(void* const* d_in, const int* in_sizes, int n_in,
                              void* d_out, int out_size, void* d_ws, size_t ws_size,
                              hipStream_t stream) {
    const float* x   = (const float*)d_in[0];
    const int*   ei  = (const int*)d_in[1];
    const float* W1  = (const float*)d_in[2];
    const float* b1  = (const float*)d_in[3];
    const float* W2  = (const float*)d_in[4];
    const float* bb2 = (const float*)d_in[5];
    float* out = (float*)d_out;

    const int n  = in_sizes[0] / 128;   // 50000
    const int E  = in_sizes[1] / 2;     // 800000
    const int NS = n * 16;

    const int* srcp = ei;
    const int* dstp = ei + E;

    const int nbuck = (n + BKT_SIZE - 1) >> BKT_SHIFT;
    const int nbA   = (E + CHUNK - 1) / CHUNK;
    const int m     = nbuck * nbA;
    const int nbS   = (m + 255) / 256;

    char* wsb = (char*)d_ws;
    // layout: barr(4096) | hist[m] | hofs[m+1] | bsum[1024] | rowptr[n+1] | dis[n]
    //         | zb[9*NS u16] | bucketed[E int2] | ecol[E u32]
    int*   barr   = (int*)wsb;
    int*   hist   = (int*)(wsb + 4096);
    int*   hofs   = (int*)(wsb + 4096 + (size_t)4 * m);
    int*   bsum   = (int*)(wsb + 4096 + (size_t)4 * (2 * m + 1));
    int*   rowptr = (int*)(wsb + 4096 + (size_t)4 * (2 * m + 1 + 1024));
    float* dis    = (float*)(wsb + 4096 + (size_t)4 * (2 * m + 1 + 1024 + n + 1));
    size_t zoffb  = align16(4096 + (size_t)4 * (2 * m + 1 + 1024 + 2 * n + 1));
    u16*   zb     = (u16*)(wsb + zoffb);
    size_t bkoff  = align16(zoffb + (size_t)2 * 9 * NS);
    int2*  bucketed = (int2*)(wsb + bkoff);
    size_t ecooff = align16(bkoff + (size_t)8 * E);
    u32*   ecol   = (u32*)(wsb + ecooff);
    size_t need   = ecooff + (size_t)4 * E;

    if (ws_size >= need && nbuck <= 512 && nbS <= 1024) {
        hipMemsetAsync(barr, 0, 4096, stream);
        // ---- proven multi-kernel CSR build (zero global atomics) ----
        hist_kernel<<<nbA, 256, 0, stream>>>(dstp, hist, E, nbA, nbuck);
        scanA_kernel<<<nbS, 256, 0, stream>>>(hist, hofs, bsum, m);
        scanB_kernel<<<1, 1024, 0, stream>>>(bsum, nbS);
        scanC_kernel<<<nbS, 256, 0, stream>>>(hofs, bsum, m);
        bucket_scatter_kernel<<<nbA, 256, 0, stream>>>(srcp, dstp, hofs, bucketed, E, nbA, nbuck);
        csr_finalize_kernel<<<nbuck, 256, 0, stream>>>(bucketed, hofs, rowptr, dis, ecol, E, nbA, nbuck, n);
        // ---- persistent compute kernel (gemm1 + 6 hops + gemm2, 7 barriers) ----
        compute_kernel<<<CGRID, 256, 0, stream>>>(
            x, W1, b1, W2, bb2, out, barr, rowptr, ecol, dis, zb, n, NS);
    } else {
        // ---------- fp32 atomic fallback ----------
        int gemm_blocks = (n + 127) / 128;
        float* ws = (float*)d_ws;
        float* dis2 = ws;
        size_t z2off = ((size_t)n + 3) & ~(size_t)3;
        float* z2 = ws + z2off;
        hipMemsetAsync(dis2, 0, n * sizeof(float), stream);
        deg_kernel<<<(E + 255) / 256, 256, 0, stream>>>(dstp, dis2, E);
        disf_kernel<<<(n + 255) / 256, 256, 0, stream>>>(dis2, n);
        gemm1_f32_kernel<<<gemm_blocks, 256, 0, stream>>>(x, W1, z2, n, NS);
        int sb = (16 * E + 255) / 256;
        spmm_atomic_kernel<<<sb, 256, 0, stream>>>(z2 + 3 * NS, z2 + 2 * NS, srcp, dstp, dis2, E);
        spmm_atomic_kernel<<<sb, 256, 0, stream>>>(z2 + 2 * NS, z2 + 1 * NS, srcp, dstp, dis2, E);
        spmm_atomic_kernel<<<sb, 256, 0, stream>>>(z2 + 1 * NS, z2,          srcp, dstp, dis2, E);
        bias_relu_kernel<<<(NS + 255) / 256, 256, 0, stream>>>(z2, b1, NS);
        hipMemsetAsync(z2 + NS, 0, (size_t)3 * NS * sizeof(float), stream);
        spmm_atomic_kernel<<<sb, 256, 0, stream>>>(z2,          z2 + NS,     srcp, dstp, dis2, E);
        spmm_atomic_kernel<<<sb, 256, 0, stream>>>(z2 + NS,     z2 + 2 * NS, srcp, dstp, dis2, E);
        spmm_atomic_kernel<<<sb, 256, 0, stream>>>(z2 + 2 * NS, z2 + 3 * NS, srcp, dstp, dis2, E);
        gemm2_f32_kernel<<<gemm_blocks, 256, 0, stream>>>(z2, W2, bb2, out, n, NS);
    }
}